// Round 10
// baseline (208.085 us; speedup 1.0000x reference)
//
#include <hip/hip_runtime.h>

constexpr int Bc = 2, Sc = 4096, Dmc = 768, Hc = 12, HDc = 64, Wc = 256, Gc = 16;
constexpr int NCH = 16, CHK = 256;     // split-K for global rows
constexpr float LOG2E = 1.4426950408889634f;
constexpr float SCALE2q = 0.125f * LOG2E;   // q-scale in exp2 domain
constexpr float NEG2c = -10000.0f * LOG2E;  // mask addend in exp2 domain

typedef __attribute__((ext_vector_type(8))) short s16x8;
typedef __attribute__((ext_vector_type(4))) short s16x4;
typedef __attribute__((ext_vector_type(4))) float f32x4;
typedef __attribute__((ext_vector_type(2))) unsigned int u32x2;

#define DEVINL __device__ __forceinline__

DEVINL float b2f(short x) {
  unsigned int u = ((unsigned int)(unsigned short)x) << 16;
  return __builtin_bit_cast(float, u);
}
DEVINL short f2b(float f) {
  unsigned int u = __builtin_bit_cast(unsigned int, f);
  unsigned int r = (u + 0x7fffu + ((u >> 16) & 1u)) >> 16;
  return (short)r;
}
DEVINL void gload16(const short* g, const short* l) {
  __builtin_amdgcn_global_load_lds(
      (const __attribute__((address_space(1))) void*)g,
      (__attribute__((address_space(3))) void*)l, 16, 0, 0);
}

// ---------------- prep: f32 -> bf16 elementwise ----------------
__global__ __launch_bounds__(256) void conv_bf16(
    const float* __restrict__ src, short* __restrict__ dst)
{
  const size_t i = ((size_t)blockIdx.x * 256 + threadIdx.x) * 8;
  f32x4 a = *(const f32x4*)(src + i);
  f32x4 c = *(const f32x4*)(src + i + 4);
  s16x8 r;
#pragma unroll
  for (int u = 0; u < 4; ++u) { r[u] = f2b(a[u]); r[4 + u] = f2b(c[u]); }
  *(s16x8*)(dst + i) = r;
}

// ---------------- prep: W[k][n] f32 -> Wt[n][k] bf16 ----------------
__global__ __launch_bounds__(256) void transpose_w(
    const float* __restrict__ W0, const float* __restrict__ W1, const float* __restrict__ W2,
    short* __restrict__ T0, short* __restrict__ T1, short* __restrict__ T2)
{
  const float* W = blockIdx.z == 0 ? W0 : (blockIdx.z == 1 ? W1 : W2);
  short* T = blockIdx.z == 0 ? T0 : (blockIdx.z == 1 ? T1 : T2);
  __shared__ short t[32][33];
  const int k0 = blockIdx.x * 32, n0 = blockIdx.y * 32;
  const int a = threadIdx.x >> 3, cg = (threadIdx.x & 7) * 4;
  f32x4 v = *(const f32x4*)&W[(size_t)(k0 + a) * Dmc + n0 + cg];
#pragma unroll
  for (int u = 0; u < 4; ++u) t[a][cg + u] = f2b(v[u]);
  __syncthreads();
  s16x4 s;
#pragma unroll
  for (int u = 0; u < 4; ++u) s[u] = t[cg + u][a];
  *(s16x4*)&T[(size_t)(n0 + a) * Dmc + k0 + cg] = s;
}

// ---------------- merged projection GEMM via global_load_lds -----------------
__global__ __launch_bounds__(256) void gemm_fused(
    const short* __restrict__ X, const short* __restrict__ Wt,
    const float* __restrict__ b0, const float* __restrict__ b1, const float* __restrict__ b2,
    short* __restrict__ Y0, float scale0)
{
  __shared__ short lds[24576];   // 2 bufs x (A 8192 + B 4096 shorts)
  char* ldsb = (char*)lds;
  const int tid = threadIdx.x, lane = tid & 63, wid = tid >> 6;
  const int gy = gridDim.y;

  const int rawd = blockIdx.x + 64 * blockIdx.y;
  const int wgid = (rawd & 7) * (gy * 8) + (rawd >> 3);
  const int mi0 = wgid / gy, ny = wgid - mi0 * gy;
  const int m0 = mi0 * 128;
  const int nch = ny / 12, ncol = (ny % 12) * 64;
  const int n0g = ny * 64;

  short* Y = Y0 + (size_t)nch * 6291456;
  const float* bias = nch == 0 ? b0 : (nch == 1 ? b1 : b2);
  const float scale = nch == 0 ? scale0 : 1.0f;

  const int lr = lane & 15, lq = lane >> 4;
  const int wm = (wid & 1) * 64, wn = (wid >> 1) * 32;

  const int l8 = lane >> 3, l7 = lane & 7;
  const int colsh = ((l7 * 16) ^ (l8 << 4)) >> 1;
  const short* Aptr[4];
  const short* Bptr[2];
#pragma unroll
  for (int i = 0; i < 4; ++i)
    Aptr[i] = X + (size_t)(m0 + wid * 32 + i * 8 + l8) * Dmc + colsh;
#pragma unroll
  for (int i = 0; i < 2; ++i)
    Bptr[i] = Wt + (size_t)(n0g + wid * 16 + i * 8 + l8) * Dmc + colsh;

  int arb[4][2], brb[2][2];
#pragma unroll
  for (int mi = 0; mi < 4; ++mi)
#pragma unroll
    for (int ks = 0; ks < 2; ++ks) {
      int row = wm + mi * 16 + lr;
      arb[mi][ks] = row * 128 + ((lq * 16 + ks * 64) ^ ((row & 7) << 4));
    }
#pragma unroll
  for (int ni = 0; ni < 2; ++ni)
#pragma unroll
    for (int ks = 0; ks < 2; ++ks) {
      int row = wn + ni * 16 + lr;
      brb[ni][ks] = 16384 + row * 128 + ((lq * 16 + ks * 64) ^ ((row & 7) << 4));
    }

  f32x4 acc[4][2] = {};

  auto issue = [&](int kt, int buf) {
    const int ko = kt * 64, bo = buf * 12288;
#pragma unroll
    for (int i = 0; i < 4; ++i) gload16(Aptr[i] + ko, &lds[bo + wid * 2048 + i * 512]);
#pragma unroll
    for (int i = 0; i < 2; ++i) gload16(Bptr[i] + ko, &lds[bo + 8192 + wid * 1024 + i * 512]);
  };

  issue(0, 0);
  for (int kt = 0; kt < 12; ++kt) {
    const int buf = kt & 1, bo = buf * 24576;
    asm volatile("s_waitcnt vmcnt(0)" ::: "memory");
    __syncthreads();
    if (kt < 11) issue(kt + 1, buf ^ 1);
#pragma unroll
    for (int ks = 0; ks < 2; ++ks) {
      s16x8 af[4], bf[2];
#pragma unroll
      for (int mi = 0; mi < 4; ++mi) af[mi] = *(const s16x8*)(ldsb + bo + arb[mi][ks]);
#pragma unroll
      for (int ni = 0; ni < 2; ++ni) bf[ni] = *(const s16x8*)(ldsb + bo + brb[ni][ks]);
#pragma unroll
      for (int mi = 0; mi < 4; ++mi)
#pragma unroll
        for (int ni = 0; ni < 2; ++ni)
          acc[mi][ni] = __builtin_amdgcn_mfma_f32_16x16x32_bf16(af[mi], bf[ni], acc[mi][ni], 0, 0, 0);
    }
  }

#pragma unroll
  for (int mi = 0; mi < 4; ++mi)
#pragma unroll
    for (int ni = 0; ni < 2; ++ni) {
      int col = ncol + wn + ni * 16 + lr;
      float bv_ = bias[col];
#pragma unroll
      for (int r = 0; r < 4; ++r) {
        int row = m0 + wm + mi * 16 + lq * 4 + r;
        Y[(size_t)row * Dmc + col] = f2b((acc[mi][ni][r] + bv_) * scale);
      }
    }
}

// ---------------- qg projection (exp2-domain scale) ----------------
__global__ __launch_bounds__(256) void qg_proj(
    const float* __restrict__ hs, const float* __restrict__ Wqg,
    const float* __restrict__ bqg, float* __restrict__ qg)
{
  const int row = blockIdx.x;
  const int b = row / Gc, i = row % Gc;
  const int tid = threadIdx.x;
  const int n = blockIdx.y * 128 + (tid & 127);
  const int half = tid >> 7;
  __shared__ float x[Dmc];
  __shared__ float part[128];
  for (int c = tid; c < Dmc; c += 256)
    x[c] = b2f(f2b(hs[((size_t)(b * Sc + i)) * Dmc + c]));
  __syncthreads();
  float acc = 0.f;
#pragma unroll 4
  for (int c = half * 384; c < half * 384 + 384; ++c)
    acc = fmaf(x[c], b2f(f2b(Wqg[(size_t)c * Dmc + n])), acc);
  if (half) part[tid & 127] = acc;
  __syncthreads();
  if (!half)
    qg[(size_t)row * Dmc + n] = (acc + part[tid] + bqg[n]) * SCALE2q;
}

// ---------------- MFMA banded attention v4: QBLK=128 ----------------
// 704 cols = 11 chunks x 64: 0..15 global keys; 16..655 window (kp2=q0-272+c);
// 656..703 dead. Each wave: 32 queries (2 x 16-q tiles). K-frags and V-frags
// are reused across both q-tiles.
__global__ __launch_bounds__(256) void local_attn_mfma(
    const short* __restrict__ q, const short* __restrict__ k,
    const short* __restrict__ v, float* __restrict__ out)
{
  const int raw = blockIdx.x + 32 * (blockIdx.y + 12 * blockIdx.z);
  const int swz = (raw & 7) * 96 + (raw >> 3);
  const int q0 = (swz & 31) * 128;
  const int h = (swz >> 5) % 12, b = swz / 384;
  const int tid = threadIdx.x, lane = tid & 63, wid = tid >> 6;

  __shared__ short Ks[4096];      // [64 key][64 d], XOR-swizzled
  __shared__ short Vt[4096];      // [64 d][64 key], XOR-swizzled
  __shared__ short Ps[4][2048];   // per wave: 2 tiles x [16 q][64 k]
  char* KsB = (char*)Ks;
  char* VtB = (char*)Vt;

  const int ql = lane & 15;
  const int lg = lane >> 4;

  s16x8 qf[2][2];
#pragma unroll
  for (int t = 0; t < 2; ++t) {
    const short* qp = q + ((size_t)(b * Sc + q0 + wid * 32 + t * 16 + ql)) * Dmc + h * HDc + lg * 8;
    qf[t][0] = *(const s16x8*)qp;
    qf[t][1] = *(const s16x8*)(qp + 32);
  }

  f32x4 oacc[2][4] = {};
  float m_run[2] = {-INFINITY, -INFINITY}, l_run[2] = {0.f, 0.f};

  const int krow = tid >> 3, kcol16 = (tid & 7) * 16;
  const int vp = tid & 31, vo = tid >> 5;
  const size_t hoff = (size_t)h * HDc;
  const size_t brow = (size_t)b * Sc;

  auto keyof = [&](int c) {
    int key = (c < Gc) ? c : q0 - 272 + c;
    return min(max(key, 0), Sc - 1);
  };

  s16x8 kreg0, kreg1, vreg0, vreg1;
  auto loadRegs = [&](int ch) {
    kreg0 = *(const s16x8*)(k + (brow + keyof(ch * 64 + krow))      * Dmc + hoff + (kcol16 >> 1));
    kreg1 = *(const s16x8*)(k + (brow + keyof(ch * 64 + 32 + krow)) * Dmc + hoff + (kcol16 >> 1));
    vreg0 = *(const s16x8*)(v + (brow + keyof(ch * 64 + 2 * vp))     * Dmc + hoff + vo * 8);
    vreg1 = *(const s16x8*)(v + (brow + keyof(ch * 64 + 2 * vp + 1)) * Dmc + hoff + vo * 8);
  };

  loadRegs(0);

  for (int ch = 0; ch < 11; ++ch) {
    __syncthreads();
    *(s16x8*)(KsB + krow * 128        + (kcol16 ^ ((krow & 7) << 4))) = kreg0;
    *(s16x8*)(KsB + (krow + 32) * 128 + (kcol16 ^ ((krow & 7) << 4))) = kreg1;
#pragma unroll
    for (int j = 0; j < 8; ++j) {
      int d = vo * 8 + j;
      unsigned int wrd = (unsigned int)(unsigned short)vreg0[j] |
                         ((unsigned int)(unsigned short)vreg1[j] << 16);
      *(unsigned int*)(VtB + d * 128 + ((4 * vp) ^ (j << 4))) = wrd;
    }
    if (ch < 10) loadRegs(ch + 1);
    __syncthreads();

    // ---- S^T: 4 key-tiles x 2 q-tiles; K-frag reused across q-tiles ----
    f32x4 sac[2][4] = {};
#pragma unroll
    for (int kt = 0; kt < 4; ++kt) {
      int row = kt * 16 + ql;
#pragma unroll
      for (int sl = 0; sl < 2; ++sl) {
        s16x8 af = *(const s16x8*)(KsB + row * 128 + ((lg * 16 + sl * 64) ^ ((row & 7) << 4)));
        sac[0][kt] = __builtin_amdgcn_mfma_f32_16x16x32_bf16(af, qf[0][sl], sac[0][kt], 0, 0, 0);
        sac[1][kt] = __builtin_amdgcn_mfma_f32_16x16x32_bf16(af, qf[1][sl], sac[1][kt], 0, 0, 0);
      }
    }

    // ---- mask (interior chunks 3..7 of interior q-blocks skip) ----
    bool needMask = (ch < 3) | (ch > 7) | (q0 < 272) | (q0 > Sc - 433);
    if (needMask) {
#pragma unroll
      for (int t = 0; t < 2; ++t) {
        int qr = wid * 32 + t * 16 + ql;
#pragma unroll
        for (int kt = 0; kt < 4; ++kt)
#pragma unroll
          for (int r = 0; r < 4; ++r) {
            int c = ch * 64 + kt * 16 + lg * 4 + r;
            if (c >= Gc) {
              float sv = sac[t][kt][r];
              int jj = c - Gc - qr;
              int kp2 = q0 - 272 + c;
              bool ok = (jj >= 0) & (jj <= 2 * Wc) & (kp2 >= 0) & (kp2 < Sc);
              sac[t][kt][r] = ok ? (sv + ((kp2 < Gc) ? NEG2c : 0.f)) : -INFINITY;
            }
          }
      }
    }

    // ---- online softmax per q-tile ----
    float cm[2];
#pragma unroll
    for (int t = 0; t < 2; ++t) {
      float m_ = -INFINITY;
#pragma unroll
      for (int kt = 0; kt < 4; ++kt)
#pragma unroll
        for (int r = 0; r < 4; ++r) m_ = fmaxf(m_, sac[t][kt][r]);
      m_ = fmaxf(m_, __shfl_xor(m_, 16));
      m_ = fmaxf(m_, __shfl_xor(m_, 32));
      cm[t] = m_;
    }

    if (__all((cm[0] <= m_run[0] + 11.5f) & (cm[1] <= m_run[1] + 11.5f))) {
#pragma unroll
      for (int t = 0; t < 2; ++t) {
        float cl = 0.f;
#pragma unroll
        for (int kt = 0; kt < 4; ++kt)
#pragma unroll
          for (int r = 0; r < 4; ++r) {
            float p = exp2f(sac[t][kt][r] - m_run[t]);
            sac[t][kt][r] = p;
            cl += p;
          }
        cl += __shfl_xor(cl, 16);
        cl += __shfl_xor(cl, 32);
        l_run[t] += cl;
      }
    } else {
#pragma unroll
      for (int t = 0; t < 2; ++t) {
        float m_new = fmaxf(m_run[t], cm[t]);
        float scale = exp2f(m_run[t] - m_new);
        float cl = 0.f;
#pragma unroll
        for (int kt = 0; kt < 4; ++kt)
#pragma unroll
          for (int r = 0; r < 4; ++r) {
            float p = exp2f(sac[t][kt][r] - m_new);
            sac[t][kt][r] = p;
            cl += p;
          }
        cl += __shfl_xor(cl, 16);
        cl += __shfl_xor(cl, 32);
        l_run[t] = l_run[t] * scale + cl;
        m_run[t] = m_new;
#pragma unroll
        for (int rr = 0; rr < 4; ++rr) {
          float os = __shfl(scale, lg * 4 + rr);
#pragma unroll
          for (int dt = 0; dt < 4; ++dt) oacc[t][dt][rr] *= os;
        }
      }
    }

    // ---- P -> bf16 (cvt_pk) into per-wave Ps; then PV with V-frag reuse ----
    char* PsB = (char*)Ps[wid];
#pragma unroll
    for (int t = 0; t < 2; ++t)
#pragma unroll
      for (int kt = 0; kt < 4; ++kt) {
        u32x2 pw;
        asm("v_cvt_pk_bf16_f32 %0, %1, %2" : "=v"(pw.x) : "v"(sac[t][kt][0]), "v"(sac[t][kt][1]));
        asm("v_cvt_pk_bf16_f32 %0, %1, %2" : "=v"(pw.y) : "v"(sac[t][kt][2]), "v"(sac[t][kt][3]));
        *(u32x2*)(PsB + t * 2048 + ql * 128 + ((kt * 32 + lg * 8) ^ ((ql & 7) << 4))) = pw;
      }
    s16x8 pf[2][2];
#pragma unroll
    for (int t = 0; t < 2; ++t)
#pragma unroll
      for (int ks = 0; ks < 2; ++ks)
        pf[t][ks] = *(const s16x8*)(PsB + t * 2048 + ql * 128 + ((ks * 64 + lg * 16) ^ ((ql & 7) << 4)));
#pragma unroll
    for (int dt = 0; dt < 4; ++dt) {
      int d = dt * 16 + ql;
#pragma unroll
      for (int ks = 0; ks < 2; ++ks) {
        s16x8 vf = *(const s16x8*)(VtB + d * 128 + ((ks * 64 + lg * 16) ^ ((d & 7) << 4)));
        oacc[0][dt] = __builtin_amdgcn_mfma_f32_16x16x32_bf16(pf[0][ks], vf, oacc[0][dt], 0, 0, 0);
        oacc[1][dt] = __builtin_amdgcn_mfma_f32_16x16x32_bf16(pf[1][ks], vf, oacc[1][dt], 0, 0, 0);
      }
    }
  }

#pragma unroll
  for (int t = 0; t < 2; ++t) {
    float inv = 1.f / l_run[t];
#pragma unroll
    for (int rr = 0; rr < 4; ++rr) {
      float oi = __shfl(inv, lg * 4 + rr);
      int row = q0 + wid * 32 + t * 16 + lg * 4 + rr;
      float* op = out + ((size_t)(b * Sc + row)) * Dmc + h * HDc + ql;
#pragma unroll
      for (int dt = 0; dt < 4; ++dt)
        op[dt * 16] = oacc[t][dt][rr] * oi;
    }
  }
}

// ---------------- global rows, split-K phase A ----------------
__global__ __launch_bounds__(256) void global_attn_part(
    const float* __restrict__ qg, const short* __restrict__ kg,
    const short* __restrict__ vg, float* __restrict__ pml, float* __restrict__ po)
{
  const int ch = blockIdx.x & (NCH - 1);
  const int i  = blockIdx.x >> 4;
  const int h = blockIdx.y, b = blockIdx.z;
  const int tid = threadIdx.x, lane = tid & 63, wid = tid >> 6;

  __shared__ float qrow[64];
  __shared__ float pls[CHK];
  __shared__ float red[8];
  __shared__ float osum[4][64];

  if (tid < 64) qrow[tid] = qg[(size_t)(b * Gc + i) * Dmc + h * HDc + tid];
  __syncthreads();

  const int sk = ch * CHK + tid;
  const s16x8* kr = (const s16x8*)(kg + ((size_t)(b * Sc + sk)) * Dmc + h * HDc);
  float acc = 0.f;
#pragma unroll
  for (int c = 0; c < 8; ++c) {
    s16x8 kv = kr[c];
#pragma unroll
    for (int u = 0; u < 8; ++u) acc = fmaf(qrow[c * 8 + u], b2f(kv[u]), acc);
  }

  float m = acc;
#pragma unroll
  for (int off = 32; off > 0; off >>= 1) m = fmaxf(m, __shfl_xor(m, off));
  if (lane == 0) red[wid] = m;
  __syncthreads();
  m = fmaxf(fmaxf(red[0], red[1]), fmaxf(red[2], red[3]));

  float p = exp2f(acc - m);
  pls[tid] = p;
  float ls = p;
#pragma unroll
  for (int off = 32; off > 0; off >>= 1) ls += __shfl_xor(ls, off);
  if (lane == 0) red[4 + wid] = ls;
  __syncthreads();
  const float l = red[4] + red[5] + red[6] + red[7];

  const int jg = tid >> 3, db = (tid & 7) * 8;
  float o[8] = {};
  const short* vb2 = vg + ((size_t)(b * Sc + ch * CHK + jg * 8)) * Dmc + h * HDc + db;
#pragma unroll
  for (int jj = 0; jj < 8; ++jj) {
    float pw = pls[jg * 8 + jj];
    s16x8 vv = *(const s16x8*)(vb2 + (size_t)jj * Dmc);
#pragma unroll
    for (int u = 0; u < 8; ++u) o[u] = fmaf(pw, b2f(vv[u]), o[u]);
  }
#pragma unroll
  for (int mk = 8; mk <= 32; mk <<= 1)
#pragma unroll
    for (int u = 0; u < 8; ++u) o[u] += __shfl_xor(o[u], mk);
  if ((lane & 56) == 0) {
#pragma unroll
    for (int u = 0; u < 8; ++u) osum[wid][(lane & 7) * 8 + u] = o[u];
  }
  __syncthreads();

  const size_t slot = (((size_t)(b * Hc + h) * Gc + i) * NCH + ch);
  if (tid < 64)
    po[slot * 64 + tid] = osum[0][tid] + osum[1][tid] + osum[2][tid] + osum[3][tid];
  if (tid == 0) { pml[slot * 2] = m; pml[slot * 2 + 1] = l; }
}

// ---------------- global rows, split-K phase B ----------------
__global__ __launch_bounds__(64) void global_attn_comb(
    const float* __restrict__ pml, const float* __restrict__ po,
    float* __restrict__ out)
{
  const int i = blockIdx.x, h = blockIdx.y, b = blockIdx.z;
  const int d = threadIdx.x;
  const size_t base = ((size_t)(b * Hc + h) * Gc + i) * NCH;

  float m = -INFINITY;
#pragma unroll
  for (int ch = 0; ch < NCH; ++ch) m = fmaxf(m, pml[(base + ch) * 2]);
  float l = 0.f, o = 0.f;
#pragma unroll
  for (int ch = 0; ch < NCH; ++ch) {
    float wgt = exp2f(pml[(base + ch) * 2] - m);
    l = fmaf(pml[(base + ch) * 2 + 1], wgt, l);
    o = fmaf(po[(base + ch) * 64 + d], wgt, o);
  }
  out[((size_t)(b * Sc + i)) * Dmc + h * HDc + d] = o / l;
}

extern "C" void kernel_launch(void* const* d_in, const int* in_sizes, int n_in,
                              void* d_out, int out_size, void* d_ws, size_t ws_size,
                              hipStream_t stream) {
  const float* hs  = (const float*)d_in[0];
  const float* Wq  = (const float*)d_in[1];
  const float* bq  = (const float*)d_in[2];
  const float* Wk  = (const float*)d_in[3];
  const float* bk  = (const float*)d_in[4];
  const float* Wv  = (const float*)d_in[5];
  const float* bv  = (const float*)d_in[6];
  const float* Wqg = (const float*)d_in[7];
  const float* bqg = (const float*)d_in[8];
  const float* Wkg = (const float*)d_in[9];
  const float* bkg = (const float*)d_in[10];
  const float* Wvg = (const float*)d_in[11];
  const float* bvg = (const float*)d_in[12];
  float* out = (float*)d_out;

  char* ws = (char*)d_ws;
  const size_t bufB = (size_t)Bc * Sc * Dmc * sizeof(short);   // 12,582,912
  short* hsb = (short*)(ws);
  short* s1  = (short*)(ws + bufB);        // q -> kg
  short* s2  = (short*)(ws + 2 * bufB);    // k -> vg
  short* s3  = (short*)(ws + 3 * bufB);    // v -> {qg,pml,po | Wt_kg,Wt_vg}

  short* wtA = (short*)d_out;              // Wt_{q,k,v} contiguous (d_out free pre-attn)
  short* wtB = wtA + (size_t)Dmc * Dmc;
  short* wtC = wtB + (size_t)Dmc * Dmc;
  float* qg  = (float*)(ws + 3 * bufB);
  float* pml = (float*)(ws + 3 * bufB + 98304);
  float* po  = (float*)(ws + 3 * bufB + 147456);
  short* wtD = (short*)(ws + 3 * bufB + (4u << 20));   // Wt_{kg,vg} contiguous
  short* wtE = wtD + (size_t)Dmc * Dmc;

  dim3 bb(256);
  conv_bf16<<<dim3(3072), bb, 0, stream>>>(hs, hsb);
  transpose_w<<<dim3(24, 24, 3), bb, 0, stream>>>(Wq, Wk, Wv, wtA, wtB, wtC);

  gemm_fused<<<dim3(64, 36), bb, 0, stream>>>(hsb, wtA, bq, bk, bv, s1, SCALE2q);

  local_attn_mfma<<<dim3(32, Hc, Bc), bb, 0, stream>>>(s1, s2, s3, out);

  transpose_w<<<dim3(24, 24, 2), bb, 0, stream>>>(Wkg, Wvg, Wvg, wtD, wtE, wtE);
  gemm_fused<<<dim3(64, 24), bb, 0, stream>>>(hsb, wtD, bkg, bvg, bvg, s1, 1.0f);

  qg_proj<<<dim3(Bc * Gc, Dmc / 128), bb, 0, stream>>>(hs, Wqg, bqg, qg);
  global_attn_part<<<dim3(Gc * NCH, Hc, Bc), bb, 0, stream>>>(qg, s1, s2, pml, po);
  global_attn_comb<<<dim3(Gc, Hc, Bc), dim3(64), 0, stream>>>(pml, po, out);
}

// Round 12
// 200.885 us; speedup vs baseline: 1.0358x; 1.0358x over previous
//
#include <hip/hip_runtime.h>

constexpr int Bc = 2, Sc = 4096, Dmc = 768, Hc = 12, HDc = 64, Wc = 256, Gc = 16;
constexpr int NCH = 16, CHK = 256;     // split-K for global rows
constexpr float LOG2E = 1.4426950408889634f;
constexpr float SCALE2q = 0.125f * LOG2E;   // q-scale in exp2 domain
constexpr float NEG2c = -10000.0f * LOG2E;  // mask addend in exp2 domain

typedef __attribute__((ext_vector_type(8))) short s16x8;
typedef __attribute__((ext_vector_type(4))) short s16x4;
typedef __attribute__((ext_vector_type(4))) float f32x4;
typedef __attribute__((ext_vector_type(2))) unsigned int u32x2;

#define DEVINL __device__ __forceinline__

DEVINL float b2f(short x) {
  unsigned int u = ((unsigned int)(unsigned short)x) << 16;
  return __builtin_bit_cast(float, u);
}
DEVINL short f2b(float f) {
  unsigned int u = __builtin_bit_cast(unsigned int, f);
  unsigned int r = (u + 0x7fffu + ((u >> 16) & 1u)) >> 16;
  return (short)r;
}
DEVINL void gload16(const short* g, const short* l) {
  __builtin_amdgcn_global_load_lds(
      (const __attribute__((address_space(1))) void*)g,
      (__attribute__((address_space(3))) void*)l, 16, 0, 0);
}

// ---------------- prep: f32 -> bf16 elementwise ----------------
__global__ __launch_bounds__(256) void conv_bf16(
    const float* __restrict__ src, short* __restrict__ dst)
{
  const size_t i = ((size_t)blockIdx.x * 256 + threadIdx.x) * 8;
  f32x4 a = *(const f32x4*)(src + i);
  f32x4 c = *(const f32x4*)(src + i + 4);
  s16x8 r;
#pragma unroll
  for (int u = 0; u < 4; ++u) { r[u] = f2b(a[u]); r[4 + u] = f2b(c[u]); }
  *(s16x8*)(dst + i) = r;
}

// ---------------- prep: W[k][n] f32 -> Wt[n][k] bf16 ----------------
__global__ __launch_bounds__(256) void transpose_w(
    const float* __restrict__ W0, const float* __restrict__ W1, const float* __restrict__ W2,
    short* __restrict__ T0, short* __restrict__ T1, short* __restrict__ T2)
{
  const float* W = blockIdx.z == 0 ? W0 : (blockIdx.z == 1 ? W1 : W2);
  short* T = blockIdx.z == 0 ? T0 : (blockIdx.z == 1 ? T1 : T2);
  __shared__ short t[32][33];
  const int k0 = blockIdx.x * 32, n0 = blockIdx.y * 32;
  const int a = threadIdx.x >> 3, cg = (threadIdx.x & 7) * 4;
  f32x4 v = *(const f32x4*)&W[(size_t)(k0 + a) * Dmc + n0 + cg];
#pragma unroll
  for (int u = 0; u < 4; ++u) t[a][cg + u] = f2b(v[u]);
  __syncthreads();
  s16x4 s;
#pragma unroll
  for (int u = 0; u < 4; ++u) s[u] = t[cg + u][a];
  *(s16x4*)&T[(size_t)(n0 + a) * Dmc + k0 + cg] = s;
}

// ---------------- merged projection GEMM via global_load_lds -----------------
__global__ __launch_bounds__(256) void gemm_fused(
    const short* __restrict__ X, const short* __restrict__ Wt,
    const float* __restrict__ b0, const float* __restrict__ b1, const float* __restrict__ b2,
    short* __restrict__ Y0, float scale0)
{
  __shared__ short lds[24576];   // 2 bufs x (A 8192 + B 4096 shorts)
  char* ldsb = (char*)lds;
  const int tid = threadIdx.x, lane = tid & 63, wid = tid >> 6;
  const int gy = gridDim.y;

  const int rawd = blockIdx.x + 64 * blockIdx.y;
  const int wgid = (rawd & 7) * (gy * 8) + (rawd >> 3);
  const int mi0 = wgid / gy, ny = wgid - mi0 * gy;
  const int m0 = mi0 * 128;
  const int nch = ny / 12, ncol = (ny % 12) * 64;
  const int n0g = ny * 64;

  short* Y = Y0 + (size_t)nch * 6291456;
  const float* bias = nch == 0 ? b0 : (nch == 1 ? b1 : b2);
  const float scale = nch == 0 ? scale0 : 1.0f;

  const int lr = lane & 15, lq = lane >> 4;
  const int wm = (wid & 1) * 64, wn = (wid >> 1) * 32;

  const int l8 = lane >> 3, l7 = lane & 7;
  const int colsh = ((l7 * 16) ^ (l8 << 4)) >> 1;
  const short* Aptr[4];
  const short* Bptr[2];
#pragma unroll
  for (int i = 0; i < 4; ++i)
    Aptr[i] = X + (size_t)(m0 + wid * 32 + i * 8 + l8) * Dmc + colsh;
#pragma unroll
  for (int i = 0; i < 2; ++i)
    Bptr[i] = Wt + (size_t)(n0g + wid * 16 + i * 8 + l8) * Dmc + colsh;

  int arb[4][2], brb[2][2];
#pragma unroll
  for (int mi = 0; mi < 4; ++mi)
#pragma unroll
    for (int ks = 0; ks < 2; ++ks) {
      int row = wm + mi * 16 + lr;
      arb[mi][ks] = row * 128 + ((lq * 16 + ks * 64) ^ ((row & 7) << 4));
    }
#pragma unroll
  for (int ni = 0; ni < 2; ++ni)
#pragma unroll
    for (int ks = 0; ks < 2; ++ks) {
      int row = wn + ni * 16 + lr;
      brb[ni][ks] = 16384 + row * 128 + ((lq * 16 + ks * 64) ^ ((row & 7) << 4));
    }

  f32x4 acc[4][2] = {};

  auto issue = [&](int kt, int buf) {
    const int ko = kt * 64, bo = buf * 12288;
#pragma unroll
    for (int i = 0; i < 4; ++i) gload16(Aptr[i] + ko, &lds[bo + wid * 2048 + i * 512]);
#pragma unroll
    for (int i = 0; i < 2; ++i) gload16(Bptr[i] + ko, &lds[bo + 8192 + wid * 1024 + i * 512]);
  };

  issue(0, 0);
  for (int kt = 0; kt < 12; ++kt) {
    const int buf = kt & 1, bo = buf * 24576;
    asm volatile("s_waitcnt vmcnt(0)" ::: "memory");
    __syncthreads();
    if (kt < 11) issue(kt + 1, buf ^ 1);
#pragma unroll
    for (int ks = 0; ks < 2; ++ks) {
      s16x8 af[4], bf[2];
#pragma unroll
      for (int mi = 0; mi < 4; ++mi) af[mi] = *(const s16x8*)(ldsb + bo + arb[mi][ks]);
#pragma unroll
      for (int ni = 0; ni < 2; ++ni) bf[ni] = *(const s16x8*)(ldsb + bo + brb[ni][ks]);
#pragma unroll
      for (int mi = 0; mi < 4; ++mi)
#pragma unroll
        for (int ni = 0; ni < 2; ++ni)
          acc[mi][ni] = __builtin_amdgcn_mfma_f32_16x16x32_bf16(af[mi], bf[ni], acc[mi][ni], 0, 0, 0);
    }
  }

#pragma unroll
  for (int mi = 0; mi < 4; ++mi)
#pragma unroll
    for (int ni = 0; ni < 2; ++ni) {
      int col = ncol + wn + ni * 16 + lr;
      float bv_ = bias[col];
#pragma unroll
      for (int r = 0; r < 4; ++r) {
        int row = m0 + wm + mi * 16 + lq * 4 + r;
        Y[(size_t)row * Dmc + col] = f2b((acc[mi][ni][r] + bv_) * scale);
      }
    }
}

// ---------------- qg projection (exp2-domain scale) ----------------
__global__ __launch_bounds__(256) void qg_proj(
    const float* __restrict__ hs, const float* __restrict__ Wqg,
    const float* __restrict__ bqg, float* __restrict__ qg)
{
  const int row = blockIdx.x;
  const int b = row / Gc, i = row % Gc;
  const int tid = threadIdx.x;
  const int n = blockIdx.y * 128 + (tid & 127);
  const int half = tid >> 7;
  __shared__ float x[Dmc];
  __shared__ float part[128];
  for (int c = tid; c < Dmc; c += 256)
    x[c] = b2f(f2b(hs[((size_t)(b * Sc + i)) * Dmc + c]));
  __syncthreads();
  float acc = 0.f;
#pragma unroll 4
  for (int c = half * 384; c < half * 384 + 384; ++c)
    acc = fmaf(x[c], b2f(f2b(Wqg[(size_t)c * Dmc + n])), acc);
  if (half) part[tid & 127] = acc;
  __syncthreads();
  if (!half)
    qg[(size_t)row * Dmc + n] = (acc + part[tid] + bqg[n]) * SCALE2q;
}

// ---------------- MFMA banded attention (r9-proven) + setprio (T5) ----------------
__global__ __launch_bounds__(256) void local_attn_mfma(
    const short* __restrict__ q, const short* __restrict__ k,
    const short* __restrict__ v, float* __restrict__ out)
{
  const int raw = blockIdx.x + 64 * (blockIdx.y + 12 * blockIdx.z);
  const int swz = (raw & 7) * 192 + (raw >> 3);
  const int q0 = (swz & 63) * 64;
  const int h = (swz >> 6) % 12, b = swz / 768;
  const int tid = threadIdx.x, lane = tid & 63, wid = tid >> 6;

  __shared__ short Ks[4096];
  __shared__ short Vt[4096];
  __shared__ short Ps[4][1024];
  char* KsB = (char*)Ks;
  char* VtB = (char*)Vt;

  const int ql = lane & 15;
  const int lg = lane >> 4;
  const int qr = wid * 16 + ql;

  s16x8 qf[2];
  {
    const short* qp = q + ((size_t)(b * Sc + q0 + qr)) * Dmc + h * HDc + lg * 8;
    qf[0] = *(const s16x8*)qp;
    qf[1] = *(const s16x8*)(qp + 32);
  }

  f32x4 oacc[4] = {};
  float m_run = -INFINITY, l_run = 0.f;

  const int krow = tid >> 3, kcol16 = (tid & 7) * 16;
  const int vp = tid & 31, vo = tid >> 5;
  const size_t hoff = (size_t)h * HDc;
  const size_t brow = (size_t)b * Sc;

  auto keyof = [&](int c) {
    int key = (c < Gc) ? c : q0 - 272 + c;
    return min(max(key, 0), Sc - 1);
  };

  s16x8 kreg0, kreg1, vreg0, vreg1;
  auto loadRegs = [&](int ch) {
    kreg0 = *(const s16x8*)(k + (brow + keyof(ch * 64 + krow))      * Dmc + hoff + (kcol16 >> 1));
    kreg1 = *(const s16x8*)(k + (brow + keyof(ch * 64 + 32 + krow)) * Dmc + hoff + (kcol16 >> 1));
    vreg0 = *(const s16x8*)(v + (brow + keyof(ch * 64 + 2 * vp))     * Dmc + hoff + vo * 8);
    vreg1 = *(const s16x8*)(v + (brow + keyof(ch * 64 + 2 * vp + 1)) * Dmc + hoff + vo * 8);
  };

  loadRegs(0);

  for (int ch = 0; ch < 10; ++ch) {
    __syncthreads();
    *(s16x8*)(KsB + krow * 128        + (kcol16 ^ ((krow & 7) << 4))) = kreg0;
    *(s16x8*)(KsB + (krow + 32) * 128 + (kcol16 ^ ((krow & 7) << 4))) = kreg1;
#pragma unroll
    for (int j = 0; j < 8; ++j) {
      int d = vo * 8 + j;
      unsigned int wrd = (unsigned int)(unsigned short)vreg0[j] |
                         ((unsigned int)(unsigned short)vreg1[j] << 16);
      *(unsigned int*)(VtB + d * 128 + ((4 * vp) ^ (j << 4))) = wrd;
    }
    if (ch < 9) loadRegs(ch + 1);
    __syncthreads();

    f32x4 sac[4] = {};
    __builtin_amdgcn_s_setprio(1);
#pragma unroll
    for (int kt = 0; kt < 4; ++kt) {
      int row = kt * 16 + ql;
#pragma unroll
      for (int sl = 0; sl < 2; ++sl) {
        s16x8 af = *(const s16x8*)(KsB + row * 128 + ((lg * 16 + sl * 64) ^ ((row & 7) << 4)));
        sac[kt] = __builtin_amdgcn_mfma_f32_16x16x32_bf16(af, qf[sl], sac[kt], 0, 0, 0);
      }
    }
    __builtin_amdgcn_s_setprio(0);

    bool needMask = (ch < 2) | (ch > 7) | (q0 < 272) | (q0 > Sc - 384);
    if (needMask) {
#pragma unroll
      for (int kt = 0; kt < 4; ++kt)
#pragma unroll
        for (int r = 0; r < 4; ++r) {
          int c = ch * 64 + kt * 16 + lg * 4 + r;
          if (c >= Gc) {
            float sv = sac[kt][r];
            int jj = c - Gc - qr;
            int kp2 = q0 - 272 + c;
            bool ok = (jj >= 0) & (jj <= 2 * Wc) & (kp2 >= 0) & (kp2 < Sc);
            sac[kt][r] = ok ? (sv + ((kp2 < Gc) ? NEG2c : 0.f)) : -INFINITY;
          }
        }
    }

    float cm = -INFINITY;
#pragma unroll
    for (int kt = 0; kt < 4; ++kt)
#pragma unroll
      for (int r = 0; r < 4; ++r) cm = fmaxf(cm, sac[kt][r]);
    cm = fmaxf(cm, __shfl_xor(cm, 16));
    cm = fmaxf(cm, __shfl_xor(cm, 32));

    if (__all(cm <= m_run + 11.5f)) {
      float cl = 0.f;
#pragma unroll
      for (int kt = 0; kt < 4; ++kt)
#pragma unroll
        for (int r = 0; r < 4; ++r) {
          float p = exp2f(sac[kt][r] - m_run);
          sac[kt][r] = p;
          cl += p;
        }
      cl += __shfl_xor(cl, 16);
      cl += __shfl_xor(cl, 32);
      l_run += cl;
    } else {
      float m_new = fmaxf(m_run, cm);
      float scale = exp2f(m_run - m_new);
      float cl = 0.f;
#pragma unroll
      for (int kt = 0; kt < 4; ++kt)
#pragma unroll
        for (int r = 0; r < 4; ++r) {
          float p = exp2f(sac[kt][r] - m_new);
          sac[kt][r] = p;
          cl += p;
        }
      cl += __shfl_xor(cl, 16);
      cl += __shfl_xor(cl, 32);
      l_run = l_run * scale + cl;
      m_run = m_new;
#pragma unroll
      for (int rr = 0; rr < 4; ++rr) {
        float os = __shfl(scale, lg * 4 + rr);
#pragma unroll
        for (int dt = 0; dt < 4; ++dt) oacc[dt][rr] *= os;
      }
    }

    // P -> bf16 via cvt_pk into per-wave Ps
    char* PsB = (char*)Ps[wid];
#pragma unroll
    for (int kt = 0; kt < 4; ++kt) {
      u32x2 pw;
      asm("v_cvt_pk_bf16_f32 %0, %1, %2" : "=v"(pw.x) : "v"(sac[kt][0]), "v"(sac[kt][1]));
      asm("v_cvt_pk_bf16_f32 %0, %1, %2" : "=v"(pw.y) : "v"(sac[kt][2]), "v"(sac[kt][3]));
      *(u32x2*)(PsB + ql * 128 + ((kt * 32 + lg * 8) ^ ((ql & 7) << 4))) = pw;
    }
    s16x8 pf[2];
#pragma unroll
    for (int ks = 0; ks < 2; ++ks)
      pf[ks] = *(const s16x8*)(PsB + ql * 128 + ((ks * 64 + lg * 16) ^ ((ql & 7) << 4)));
    __builtin_amdgcn_s_setprio(1);
#pragma unroll
    for (int dt = 0; dt < 4; ++dt) {
      int d = dt * 16 + ql;
#pragma unroll
      for (int ks = 0; ks < 2; ++ks) {
        s16x8 vf = *(const s16x8*)(VtB + d * 128 + ((ks * 64 + lg * 16) ^ ((d & 7) << 4)));
        oacc[dt] = __builtin_amdgcn_mfma_f32_16x16x32_bf16(pf[ks], vf, oacc[dt], 0, 0, 0);
      }
    }
    __builtin_amdgcn_s_setprio(0);
  }

  float inv = 1.f / l_run;
#pragma unroll
  for (int rr = 0; rr < 4; ++rr) {
    float oi = __shfl(inv, lg * 4 + rr);
    int row = q0 + wid * 16 + lg * 4 + rr;
    float* op = out + ((size_t)(b * Sc + row)) * Dmc + h * HDc + ql;
#pragma unroll
    for (int dt = 0; dt < 4; ++dt)
      op[dt * 16] = oacc[dt][rr] * oi;
  }
}

// ---------------- global rows, split-K phase A ----------------
__global__ __launch_bounds__(256) void global_attn_part(
    const float* __restrict__ qg, const short* __restrict__ kg,
    const short* __restrict__ vg, float* __restrict__ pml, float* __restrict__ po)
{
  const int ch = blockIdx.x & (NCH - 1);
  const int i  = blockIdx.x >> 4;
  const int h = blockIdx.y, b = blockIdx.z;
  const int tid = threadIdx.x, lane = tid & 63, wid = tid >> 6;

  __shared__ float qrow[64];
  __shared__ float pls[CHK];
  __shared__ float red[8];
  __shared__ float osum[4][64];

  if (tid < 64) qrow[tid] = qg[(size_t)(b * Gc + i) * Dmc + h * HDc + tid];
  __syncthreads();

  const int sk = ch * CHK + tid;
  const s16x8* kr = (const s16x8*)(kg + ((size_t)(b * Sc + sk)) * Dmc + h * HDc);
  float acc = 0.f;
#pragma unroll
  for (int c = 0; c < 8; ++c) {
    s16x8 kv = kr[c];
#pragma unroll
    for (int u = 0; u < 8; ++u) acc = fmaf(qrow[c * 8 + u], b2f(kv[u]), acc);
  }

  float m = acc;
#pragma unroll
  for (int off = 32; off > 0; off >>= 1) m = fmaxf(m, __shfl_xor(m, off));
  if (lane == 0) red[wid] = m;
  __syncthreads();
  m = fmaxf(fmaxf(red[0], red[1]), fmaxf(red[2], red[3]));

  float p = exp2f(acc - m);
  pls[tid] = p;
  float ls = p;
#pragma unroll
  for (int off = 32; off > 0; off >>= 1) ls += __shfl_xor(ls, off);
  if (lane == 0) red[4 + wid] = ls;
  __syncthreads();
  const float l = red[4] + red[5] + red[6] + red[7];

  const int jg = tid >> 3, db = (tid & 7) * 8;
  float o[8] = {};
  const short* vb2 = vg + ((size_t)(b * Sc + ch * CHK + jg * 8)) * Dmc + h * HDc + db;
#pragma unroll
  for (int jj = 0; jj < 8; ++jj) {
    float pw = pls[jg * 8 + jj];
    s16x8 vv = *(const s16x8*)(vb2 + (size_t)jj * Dmc);
#pragma unroll
    for (int u = 0; u < 8; ++u) o[u] = fmaf(pw, b2f(vv[u]), o[u]);
  }
#pragma unroll
  for (int mk = 8; mk <= 32; mk <<= 1)
#pragma unroll
    for (int u = 0; u < 8; ++u) o[u] += __shfl_xor(o[u], mk);
  if ((lane & 56) == 0) {
#pragma unroll
    for (int u = 0; u < 8; ++u) osum[wid][(lane & 7) * 8 + u] = o[u];
  }
  __syncthreads();

  const size_t slot = (((size_t)(b * Hc + h) * Gc + i) * NCH + ch);
  if (tid < 64)
    po[slot * 64 + tid] = osum[0][tid] + osum[1][tid] + osum[2][tid] + osum[3][tid];
  if (tid == 0) { pml[slot * 2] = m; pml[slot * 2 + 1] = l; }
}

// ---------------- global rows, split-K phase B ----------------
__global__ __launch_bounds__(64) void global_attn_comb(
    const float* __restrict__ pml, const float* __restrict__ po,
    float* __restrict__ out)
{
  const int i = blockIdx.x, h = blockIdx.y, b = blockIdx.z;
  const int d = threadIdx.x;
  const size_t base = ((size_t)(b * Hc + h) * Gc + i) * NCH;

  float m = -INFINITY;
#pragma unroll
  for (int ch = 0; ch < NCH; ++ch) m = fmaxf(m, pml[(base + ch) * 2]);
  float l = 0.f, o = 0.f;
#pragma unroll
  for (int ch = 0; ch < NCH; ++ch) {
    float wgt = exp2f(pml[(base + ch) * 2] - m);
    l = fmaf(pml[(base + ch) * 2 + 1], wgt, l);
    o = fmaf(po[(base + ch) * 64 + d], wgt, o);
  }
  out[((size_t)(b * Sc + i)) * Dmc + h * HDc + d] = o / l;
}

extern "C" void kernel_launch(void* const* d_in, const int* in_sizes, int n_in,
                              void* d_out, int out_size, void* d_ws, size_t ws_size,
                              hipStream_t stream) {
  const float* hs  = (const float*)d_in[0];
  const float* Wq  = (const float*)d_in[1];
  const float* bq  = (const float*)d_in[2];
  const float* Wk  = (const float*)d_in[3];
  const float* bk  = (const float*)d_in[4];
  const float* Wv  = (const float*)d_in[5];
  const float* bv  = (const float*)d_in[6];
  const float* Wqg = (const float*)d_in[7];
  const float* bqg = (const float*)d_in[8];
  const float* Wkg = (const float*)d_in[9];
  const float* bkg = (const float*)d_in[10];
  const float* Wvg = (const float*)d_in[11];
  const float* bvg = (const float*)d_in[12];
  float* out = (float*)d_out;

  char* ws = (char*)d_ws;
  const size_t bufB = (size_t)Bc * Sc * Dmc * sizeof(short);   // 12,582,912
  short* hsb = (short*)(ws);
  short* s1  = (short*)(ws + bufB);        // q -> kg
  short* s2  = (short*)(ws + 2 * bufB);    // k -> vg
  short* s3  = (short*)(ws + 3 * bufB);    // v -> {qg,pml,po | Wt_kg,Wt_vg}

  short* wtA = (short*)d_out;              // Wt_{q,k,v} contiguous (d_out free pre-attn)
  short* wtB = wtA + (size_t)Dmc * Dmc;
  short* wtC = wtB + (size_t)Dmc * Dmc;
  float* qg  = (float*)(ws + 3 * bufB);
  float* pml = (float*)(ws + 3 * bufB + 98304);
  float* po  = (float*)(ws + 3 * bufB + 147456);
  short* wtD = (short*)(ws + 3 * bufB + (4u << 20));   // Wt_{kg,vg} contiguous
  short* wtE = wtD + (size_t)Dmc * Dmc;

  dim3 bb(256);
  conv_bf16<<<dim3(3072), bb, 0, stream>>>(hs, hsb);
  transpose_w<<<dim3(24, 24, 3), bb, 0, stream>>>(Wq, Wk, Wv, wtA, wtB, wtC);

  gemm_fused<<<dim3(64, 36), bb, 0, stream>>>(hsb, wtA, bq, bk, bv, s1, SCALE2q);

  local_attn_mfma<<<dim3(64, Hc, Bc), bb, 0, stream>>>(s1, s2, s3, out);

  transpose_w<<<dim3(24, 24, 2), bb, 0, stream>>>(Wkg, Wvg, Wvg, wtD, wtE, wtE);
  gemm_fused<<<dim3(64, 24), bb, 0, stream>>>(hsb, wtD, bkg, bvg, bvg, s1, 1.0f);

  qg_proj<<<dim3(Bc * Gc, Dmc / 128), bb, 0, stream>>>(hs, Wqg, bqg, qg);
  global_attn_part<<<dim3(Gc * NCH, Hc, Bc), bb, 0, stream>>>(qg, s1, s2, pml, po);
  global_attn_comb<<<dim3(Gc, Hc, Bc), dim3(64), 0, stream>>>(pml, po, out);
}

// Round 13
// 194.154 us; speedup vs baseline: 1.0718x; 1.0347x over previous
//
#include <hip/hip_runtime.h>

constexpr int Bc = 2, Sc = 4096, Dmc = 768, Hc = 12, HDc = 64, Wc = 256, Gc = 16;
constexpr int NCH = 16, CHK = 256;     // split-K for global rows
constexpr float LOG2E = 1.4426950408889634f;
constexpr float SCALE2q = 0.125f * LOG2E;   // q-scale in exp2 domain
constexpr float NEG2c = -10000.0f * LOG2E;  // mask addend in exp2 domain

typedef __attribute__((ext_vector_type(8))) short s16x8;
typedef __attribute__((ext_vector_type(4))) short s16x4;
typedef __attribute__((ext_vector_type(4))) float f32x4;
typedef __attribute__((ext_vector_type(2))) unsigned int u32x2;

#define DEVINL __device__ __forceinline__

DEVINL float b2f(short x) {
  unsigned int u = ((unsigned int)(unsigned short)x) << 16;
  return __builtin_bit_cast(float, u);
}
DEVINL short f2b(float f) {
  unsigned int u = __builtin_bit_cast(unsigned int, f);
  unsigned int r = (u + 0x7fffu + ((u >> 16) & 1u)) >> 16;
  return (short)r;
}
DEVINL void gload16(const short* g, const short* l) {
  __builtin_amdgcn_global_load_lds(
      (const __attribute__((address_space(1))) void*)g,
      (__attribute__((address_space(3))) void*)l, 16, 0, 0);
}

// ---------------- prep: f32 -> bf16 elementwise ----------------
__global__ __launch_bounds__(256) void conv_bf16(
    const float* __restrict__ src, short* __restrict__ dst)
{
  const size_t i = ((size_t)blockIdx.x * 256 + threadIdx.x) * 8;
  f32x4 a = *(const f32x4*)(src + i);
  f32x4 c = *(const f32x4*)(src + i + 4);
  s16x8 r;
#pragma unroll
  for (int u = 0; u < 4; ++u) { r[u] = f2b(a[u]); r[4 + u] = f2b(c[u]); }
  *(s16x8*)(dst + i) = r;
}

// ---------------- prep: W[k][n] f32 -> Wt[n][k] bf16 ----------------
__global__ __launch_bounds__(256) void transpose_w(
    const float* __restrict__ W0, const float* __restrict__ W1, const float* __restrict__ W2,
    short* __restrict__ T0, short* __restrict__ T1, short* __restrict__ T2)
{
  const float* W = blockIdx.z == 0 ? W0 : (blockIdx.z == 1 ? W1 : W2);
  short* T = blockIdx.z == 0 ? T0 : (blockIdx.z == 1 ? T1 : T2);
  __shared__ short t[32][33];
  const int k0 = blockIdx.x * 32, n0 = blockIdx.y * 32;
  const int a = threadIdx.x >> 3, cg = (threadIdx.x & 7) * 4;
  f32x4 v = *(const f32x4*)&W[(size_t)(k0 + a) * Dmc + n0 + cg];
#pragma unroll
  for (int u = 0; u < 4; ++u) t[a][cg + u] = f2b(v[u]);
  __syncthreads();
  s16x4 s;
#pragma unroll
  for (int u = 0; u < 4; ++u) s[u] = t[cg + u][a];
  *(s16x4*)&T[(size_t)(n0 + a) * Dmc + k0 + cg] = s;
}

// ---------------- merged projection GEMM, 128x128 tile (m97 geometry) ---------
// X:[8192][768] bf16; Wt:[gy*128][768] bf16. BM=128, BN=128, BK=64, 4 waves.
// Single-buffer LDS 32KB; pre-swizzled global src + linear LDS dest + swizzled
// ds_read (rule #21). n-tile (128) always inside one 768-col output chunk.
__global__ __launch_bounds__(256) void gemm_fused(
    const short* __restrict__ X, const short* __restrict__ Wt,
    const float* __restrict__ b0, const float* __restrict__ b1, const float* __restrict__ b2,
    short* __restrict__ Y0, float scale0)
{
  __shared__ short lds[16384];   // A shorts [0,8192), B shorts [8192,16384)
  char* ldsb = (char*)lds;
  const int tid = threadIdx.x, lane = tid & 63, wid = tid >> 6;
  const int gy = gridDim.y;

  // bijective XCD swizzle (nwg = 64*gy, divisible by 8)
  const int rawd = blockIdx.x + 64 * blockIdx.y;
  const int wgid = (rawd & 7) * (gy * 8) + (rawd >> 3);
  const int mi0 = wgid / gy, ny = wgid - mi0 * gy;
  const int m0 = mi0 * 128;
  const int nch = ny / 6, ncol = (ny % 6) * 128;   // 768 = 6 x 128
  const int n0g = ny * 128;

  short* Y = Y0 + (size_t)nch * 6291456;
  const float* bias = nch == 0 ? b0 : (nch == 1 ? b1 : b2);
  const float scale = nch == 0 ? scale0 : 1.0f;

  const int lr = lane & 15, lq = lane >> 4;
  const int wm = (wid & 1) * 64, wn = (wid >> 1) * 64;

  // staging source (pre-swizzled column); wave w, issue i covers rows w*32+i*8+(lane>>3)
  const int l8 = lane >> 3, l7 = lane & 7;
  const int colsh = ((l7 * 16) ^ (l8 << 4)) >> 1;     // shorts
  const short* Aptr[4];
  const short* Bptr[4];
#pragma unroll
  for (int i = 0; i < 4; ++i) {
    Aptr[i] = X  + (size_t)(m0  + wid * 32 + i * 8 + l8) * Dmc + colsh;
    Bptr[i] = Wt + (size_t)(n0g + wid * 32 + i * 8 + l8) * Dmc + colsh;
  }

  // frag read byte offsets
  int arb[4][2], brb[4][2];
#pragma unroll
  for (int mi = 0; mi < 4; ++mi)
#pragma unroll
    for (int ks = 0; ks < 2; ++ks) {
      int row = wm + mi * 16 + lr;
      arb[mi][ks] = row * 128 + ((lq * 16 + ks * 64) ^ ((row & 7) << 4));
    }
#pragma unroll
  for (int ni = 0; ni < 4; ++ni)
#pragma unroll
    for (int ks = 0; ks < 2; ++ks) {
      int row = wn + ni * 16 + lr;
      brb[ni][ks] = 16384 + row * 128 + ((lq * 16 + ks * 64) ^ ((row & 7) << 4));
    }

  f32x4 acc[4][4] = {};

  for (int kt = 0; kt < 12; ++kt) {
    const int ko = kt * 64;
    if (kt) __syncthreads();             // all waves done reading previous tile
#pragma unroll
    for (int i = 0; i < 4; ++i) {
      gload16(Aptr[i] + ko, &lds[wid * 2048 + i * 512]);
      gload16(Bptr[i] + ko, &lds[8192 + wid * 2048 + i * 512]);
    }
    asm volatile("s_waitcnt vmcnt(0)" ::: "memory");
    __syncthreads();                     // tile fully landed
#pragma unroll
    for (int ks = 0; ks < 2; ++ks) {
      s16x8 af[4], bf[4];
#pragma unroll
      for (int mi = 0; mi < 4; ++mi) af[mi] = *(const s16x8*)(ldsb + arb[mi][ks]);
#pragma unroll
      for (int ni = 0; ni < 4; ++ni) bf[ni] = *(const s16x8*)(ldsb + brb[ni][ks]);
#pragma unroll
      for (int mi = 0; mi < 4; ++mi)
#pragma unroll
        for (int ni = 0; ni < 4; ++ni)
          acc[mi][ni] = __builtin_amdgcn_mfma_f32_16x16x32_bf16(af[mi], bf[ni], acc[mi][ni], 0, 0, 0);
    }
  }

#pragma unroll
  for (int mi = 0; mi < 4; ++mi)
#pragma unroll
    for (int ni = 0; ni < 4; ++ni) {
      int col = ncol + wn + ni * 16 + lr;
      float bv_ = bias[col];
#pragma unroll
      for (int r = 0; r < 4; ++r) {
        int row = m0 + wm + mi * 16 + lq * 4 + r;
        Y[(size_t)row * Dmc + col] = f2b((acc[mi][ni][r] + bv_) * scale);
      }
    }
}

// ---------------- qg projection (exp2-domain scale) ----------------
__global__ __launch_bounds__(256) void qg_proj(
    const float* __restrict__ hs, const float* __restrict__ Wqg,
    const float* __restrict__ bqg, float* __restrict__ qg)
{
  const int row = blockIdx.x;
  const int b = row / Gc, i = row % Gc;
  const int tid = threadIdx.x;
  const int n = blockIdx.y * 128 + (tid & 127);
  const int half = tid >> 7;
  __shared__ float x[Dmc];
  __shared__ float part[128];
  for (int c = tid; c < Dmc; c += 256)
    x[c] = b2f(f2b(hs[((size_t)(b * Sc + i)) * Dmc + c]));
  __syncthreads();
  float acc = 0.f;
#pragma unroll 4
  for (int c = half * 384; c < half * 384 + 384; ++c)
    acc = fmaf(x[c], b2f(f2b(Wqg[(size_t)c * Dmc + n])), acc);
  if (half) part[tid & 127] = acc;
  __syncthreads();
  if (!half)
    qg[(size_t)row * Dmc + n] = (acc + part[tid] + bqg[n]) * SCALE2q;
}

// ---------------- MFMA banded attention (r9-proven) + setprio ----------------
__global__ __launch_bounds__(256) void local_attn_mfma(
    const short* __restrict__ q, const short* __restrict__ k,
    const short* __restrict__ v, float* __restrict__ out)
{
  const int raw = blockIdx.x + 64 * (blockIdx.y + 12 * blockIdx.z);
  const int swz = (raw & 7) * 192 + (raw >> 3);
  const int q0 = (swz & 63) * 64;
  const int h = (swz >> 6) % 12, b = swz / 768;
  const int tid = threadIdx.x, lane = tid & 63, wid = tid >> 6;

  __shared__ short Ks[4096];
  __shared__ short Vt[4096];
  __shared__ short Ps[4][1024];
  char* KsB = (char*)Ks;
  char* VtB = (char*)Vt;

  const int ql = lane & 15;
  const int lg = lane >> 4;
  const int qr = wid * 16 + ql;

  s16x8 qf[2];
  {
    const short* qp = q + ((size_t)(b * Sc + q0 + qr)) * Dmc + h * HDc + lg * 8;
    qf[0] = *(const s16x8*)qp;
    qf[1] = *(const s16x8*)(qp + 32);
  }

  f32x4 oacc[4] = {};
  float m_run = -INFINITY, l_run = 0.f;

  const int krow = tid >> 3, kcol16 = (tid & 7) * 16;
  const int vp = tid & 31, vo = tid >> 5;
  const size_t hoff = (size_t)h * HDc;
  const size_t brow = (size_t)b * Sc;

  auto keyof = [&](int c) {
    int key = (c < Gc) ? c : q0 - 272 + c;
    return min(max(key, 0), Sc - 1);
  };

  s16x8 kreg0, kreg1, vreg0, vreg1;
  auto loadRegs = [&](int ch) {
    kreg0 = *(const s16x8*)(k + (brow + keyof(ch * 64 + krow))      * Dmc + hoff + (kcol16 >> 1));
    kreg1 = *(const s16x8*)(k + (brow + keyof(ch * 64 + 32 + krow)) * Dmc + hoff + (kcol16 >> 1));
    vreg0 = *(const s16x8*)(v + (brow + keyof(ch * 64 + 2 * vp))     * Dmc + hoff + vo * 8);
    vreg1 = *(const s16x8*)(v + (brow + keyof(ch * 64 + 2 * vp + 1)) * Dmc + hoff + vo * 8);
  };

  loadRegs(0);

  for (int ch = 0; ch < 10; ++ch) {
    __syncthreads();
    *(s16x8*)(KsB + krow * 128        + (kcol16 ^ ((krow & 7) << 4))) = kreg0;
    *(s16x8*)(KsB + (krow + 32) * 128 + (kcol16 ^ ((krow & 7) << 4))) = kreg1;
#pragma unroll
    for (int j = 0; j < 8; ++j) {
      int d = vo * 8 + j;
      unsigned int wrd = (unsigned int)(unsigned short)vreg0[j] |
                         ((unsigned int)(unsigned short)vreg1[j] << 16);
      *(unsigned int*)(VtB + d * 128 + ((4 * vp) ^ (j << 4))) = wrd;
    }
    if (ch < 9) loadRegs(ch + 1);
    __syncthreads();

    f32x4 sac[4] = {};
    __builtin_amdgcn_s_setprio(1);
#pragma unroll
    for (int kt = 0; kt < 4; ++kt) {
      int row = kt * 16 + ql;
#pragma unroll
      for (int sl = 0; sl < 2; ++sl) {
        s16x8 af = *(const s16x8*)(KsB + row * 128 + ((lg * 16 + sl * 64) ^ ((row & 7) << 4)));
        sac[kt] = __builtin_amdgcn_mfma_f32_16x16x32_bf16(af, qf[sl], sac[kt], 0, 0, 0);
      }
    }
    __builtin_amdgcn_s_setprio(0);

    bool needMask = (ch < 2) | (ch > 7) | (q0 < 272) | (q0 > Sc - 384);
    if (needMask) {
#pragma unroll
      for (int kt = 0; kt < 4; ++kt)
#pragma unroll
        for (int r = 0; r < 4; ++r) {
          int c = ch * 64 + kt * 16 + lg * 4 + r;
          if (c >= Gc) {
            float sv = sac[kt][r];
            int jj = c - Gc - qr;
            int kp2 = q0 - 272 + c;
            bool ok = (jj >= 0) & (jj <= 2 * Wc) & (kp2 >= 0) & (kp2 < Sc);
            sac[kt][r] = ok ? (sv + ((kp2 < Gc) ? NEG2c : 0.f)) : -INFINITY;
          }
        }
    }

    float cm = -INFINITY;
#pragma unroll
    for (int kt = 0; kt < 4; ++kt)
#pragma unroll
      for (int r = 0; r < 4; ++r) cm = fmaxf(cm, sac[kt][r]);
    cm = fmaxf(cm, __shfl_xor(cm, 16));
    cm = fmaxf(cm, __shfl_xor(cm, 32));

    if (__all(cm <= m_run + 11.5f)) {
      float cl = 0.f;
#pragma unroll
      for (int kt = 0; kt < 4; ++kt)
#pragma unroll
        for (int r = 0; r < 4; ++r) {
          float p = exp2f(sac[kt][r] - m_run);
          sac[kt][r] = p;
          cl += p;
        }
      cl += __shfl_xor(cl, 16);
      cl += __shfl_xor(cl, 32);
      l_run += cl;
    } else {
      float m_new = fmaxf(m_run, cm);
      float scale = exp2f(m_run - m_new);
      float cl = 0.f;
#pragma unroll
      for (int kt = 0; kt < 4; ++kt)
#pragma unroll
        for (int r = 0; r < 4; ++r) {
          float p = exp2f(sac[kt][r] - m_new);
          sac[kt][r] = p;
          cl += p;
        }
      cl += __shfl_xor(cl, 16);
      cl += __shfl_xor(cl, 32);
      l_run = l_run * scale + cl;
      m_run = m_new;
#pragma unroll
      for (int rr = 0; rr < 4; ++rr) {
        float os = __shfl(scale, lg * 4 + rr);
#pragma unroll
        for (int dt = 0; dt < 4; ++dt) oacc[dt][rr] *= os;
      }
    }

    char* PsB = (char*)Ps[wid];
#pragma unroll
    for (int kt = 0; kt < 4; ++kt) {
      u32x2 pw;
      asm("v_cvt_pk_bf16_f32 %0, %1, %2" : "=v"(pw.x) : "v"(sac[kt][0]), "v"(sac[kt][1]));
      asm("v_cvt_pk_bf16_f32 %0, %1, %2" : "=v"(pw.y) : "v"(sac[kt][2]), "v"(sac[kt][3]));
      *(u32x2*)(PsB + ql * 128 + ((kt * 32 + lg * 8) ^ ((ql & 7) << 4))) = pw;
    }
    s16x8 pf[2];
#pragma unroll
    for (int ks = 0; ks < 2; ++ks)
      pf[ks] = *(const s16x8*)(PsB + ql * 128 + ((ks * 64 + lg * 16) ^ ((ql & 7) << 4)));
    __builtin_amdgcn_s_setprio(1);
#pragma unroll
    for (int dt = 0; dt < 4; ++dt) {
      int d = dt * 16 + ql;
#pragma unroll
      for (int ks = 0; ks < 2; ++ks) {
        s16x8 vf = *(const s16x8*)(VtB + d * 128 + ((ks * 64 + lg * 16) ^ ((d & 7) << 4)));
        oacc[dt] = __builtin_amdgcn_mfma_f32_16x16x32_bf16(pf[ks], vf, oacc[dt], 0, 0, 0);
      }
    }
    __builtin_amdgcn_s_setprio(0);
  }

  float inv = 1.f / l_run;
#pragma unroll
  for (int rr = 0; rr < 4; ++rr) {
    float oi = __shfl(inv, lg * 4 + rr);
    int row = q0 + wid * 16 + lg * 4 + rr;
    float* op = out + ((size_t)(b * Sc + row)) * Dmc + h * HDc + ql;
#pragma unroll
    for (int dt = 0; dt < 4; ++dt)
      op[dt * 16] = oacc[dt][rr] * oi;
  }
}

// ---------------- global rows, split-K phase A ----------------
__global__ __launch_bounds__(256) void global_attn_part(
    const float* __restrict__ qg, const short* __restrict__ kg,
    const short* __restrict__ vg, float* __restrict__ pml, float* __restrict__ po)
{
  const int ch = blockIdx.x & (NCH - 1);
  const int i  = blockIdx.x >> 4;
  const int h = blockIdx.y, b = blockIdx.z;
  const int tid = threadIdx.x, lane = tid & 63, wid = tid >> 6;

  __shared__ float qrow[64];
  __shared__ float pls[CHK];
  __shared__ float red[8];
  __shared__ float osum[4][64];

  if (tid < 64) qrow[tid] = qg[(size_t)(b * Gc + i) * Dmc + h * HDc + tid];
  __syncthreads();

  const int sk = ch * CHK + tid;
  const s16x8* kr = (const s16x8*)(kg + ((size_t)(b * Sc + sk)) * Dmc + h * HDc);
  float acc = 0.f;
#pragma unroll
  for (int c = 0; c < 8; ++c) {
    s16x8 kv = kr[c];
#pragma unroll
    for (int u = 0; u < 8; ++u) acc = fmaf(qrow[c * 8 + u], b2f(kv[u]), acc);
  }

  float m = acc;
#pragma unroll
  for (int off = 32; off > 0; off >>= 1) m = fmaxf(m, __shfl_xor(m, off));
  if (lane == 0) red[wid] = m;
  __syncthreads();
  m = fmaxf(fmaxf(red[0], red[1]), fmaxf(red[2], red[3]));

  float p = exp2f(acc - m);
  pls[tid] = p;
  float ls = p;
#pragma unroll
  for (int off = 32; off > 0; off >>= 1) ls += __shfl_xor(ls, off);
  if (lane == 0) red[4 + wid] = ls;
  __syncthreads();
  const float l = red[4] + red[5] + red[6] + red[7];

  const int jg = tid >> 3, db = (tid & 7) * 8;
  float o[8] = {};
  const short* vb2 = vg + ((size_t)(b * Sc + ch * CHK + jg * 8)) * Dmc + h * HDc + db;
#pragma unroll
  for (int jj = 0; jj < 8; ++jj) {
    float pw = pls[jg * 8 + jj];
    s16x8 vv = *(const s16x8*)(vb2 + (size_t)jj * Dmc);
#pragma unroll
    for (int u = 0; u < 8; ++u) o[u] = fmaf(pw, b2f(vv[u]), o[u]);
  }
#pragma unroll
  for (int mk = 8; mk <= 32; mk <<= 1)
#pragma unroll
    for (int u = 0; u < 8; ++u) o[u] += __shfl_xor(o[u], mk);
  if ((lane & 56) == 0) {
#pragma unroll
    for (int u = 0; u < 8; ++u) osum[wid][(lane & 7) * 8 + u] = o[u];
  }
  __syncthreads();

  const size_t slot = (((size_t)(b * Hc + h) * Gc + i) * NCH + ch);
  if (tid < 64)
    po[slot * 64 + tid] = osum[0][tid] + osum[1][tid] + osum[2][tid] + osum[3][tid];
  if (tid == 0) { pml[slot * 2] = m; pml[slot * 2 + 1] = l; }
}

// ---------------- global rows, split-K phase B ----------------
__global__ __launch_bounds__(64) void global_attn_comb(
    const float* __restrict__ pml, const float* __restrict__ po,
    float* __restrict__ out)
{
  const int i = blockIdx.x, h = blockIdx.y, b = blockIdx.z;
  const int d = threadIdx.x;
  const size_t base = ((size_t)(b * Hc + h) * Gc + i) * NCH;

  float m = -INFINITY;
#pragma unroll
  for (int ch = 0; ch < NCH; ++ch) m = fmaxf(m, pml[(base + ch) * 2]);
  float l = 0.f, o = 0.f;
#pragma unroll
  for (int ch = 0; ch < NCH; ++ch) {
    float wgt = exp2f(pml[(base + ch) * 2] - m);
    l = fmaf(pml[(base + ch) * 2 + 1], wgt, l);
    o = fmaf(po[(base + ch) * 64 + d], wgt, o);
  }
  out[((size_t)(b * Sc + i)) * Dmc + h * HDc + d] = o / l;
}

extern "C" void kernel_launch(void* const* d_in, const int* in_sizes, int n_in,
                              void* d_out, int out_size, void* d_ws, size_t ws_size,
                              hipStream_t stream) {
  const float* hs  = (const float*)d_in[0];
  const float* Wq  = (const float*)d_in[1];
  const float* bq  = (const float*)d_in[2];
  const float* Wk  = (const float*)d_in[3];
  const float* bk  = (const float*)d_in[4];
  const float* Wv  = (const float*)d_in[5];
  const float* bv  = (const float*)d_in[6];
  const float* Wqg = (const float*)d_in[7];
  const float* bqg = (const float*)d_in[8];
  const float* Wkg = (const float*)d_in[9];
  const float* bkg = (const float*)d_in[10];
  const float* Wvg = (const float*)d_in[11];
  const float* bvg = (const float*)d_in[12];
  float* out = (float*)d_out;

  char* ws = (char*)d_ws;
  const size_t bufB = (size_t)Bc * Sc * Dmc * sizeof(short);   // 12,582,912
  short* hsb = (short*)(ws);
  short* s1  = (short*)(ws + bufB);        // q -> kg
  short* s2  = (short*)(ws + 2 * bufB);    // k -> vg
  short* s3  = (short*)(ws + 3 * bufB);    // v -> {qg,pml,po | Wt_kg,Wt_vg}

  short* wtA = (short*)d_out;              // Wt_{q,k,v} contiguous (d_out free pre-attn)
  short* wtB = wtA + (size_t)Dmc * Dmc;
  short* wtC = wtB + (size_t)Dmc * Dmc;
  float* qg  = (float*)(ws + 3 * bufB);
  float* pml = (float*)(ws + 3 * bufB + 98304);
  float* po  = (float*)(ws + 3 * bufB + 147456);
  short* wtD = (short*)(ws + 3 * bufB + (4u << 20));   // Wt_{kg,vg} contiguous
  short* wtE = wtD + (size_t)Dmc * Dmc;

  dim3 bb(256);
  conv_bf16<<<dim3(3072), bb, 0, stream>>>(hs, hsb);
  transpose_w<<<dim3(24, 24, 3), bb, 0, stream>>>(Wq, Wk, Wv, wtA, wtB, wtC);

  gemm_fused<<<dim3(64, 18), bb, 0, stream>>>(hsb, wtA, bq, bk, bv, s1, SCALE2q);

  local_attn_mfma<<<dim3(64, Hc, Bc), bb, 0, stream>>>(s1, s2, s3, out);

  transpose_w<<<dim3(24, 24, 2), bb, 0, stream>>>(Wkg, Wvg, Wvg, wtD, wtE, wtE);
  gemm_fused<<<dim3(64, 12), bb, 0, stream>>>(hsb, wtD, bkg, bvg, bvg, s1, 1.0f);

  qg_proj<<<dim3(Bc * Gc, Dmc / 128), bb, 0, stream>>>(hs, Wqg, bqg, qg);
  global_attn_part<<<dim3(Gc * NCH, Hc, Bc), bb, 0, stream>>>(qg, s1, s2, pml, po);
  global_attn_comb<<<dim3(Gc, Hc, Bc), dim3(64), 0, stream>>>(pml, po, out);
}

// Round 14
// 189.474 us; speedup vs baseline: 1.0982x; 1.0247x over previous
//
#include <hip/hip_runtime.h>

constexpr int Bc = 2, Sc = 4096, Dmc = 768, Hc = 12, HDc = 64, Wc = 256, Gc = 16;
constexpr int NCH = 16, CHK = 256;     // split-K for global rows
constexpr float LOG2E = 1.4426950408889634f;
constexpr float SCALE2q = 0.125f * LOG2E;   // q-scale in exp2 domain
constexpr float NEG2c = -10000.0f * LOG2E;  // mask addend in exp2 domain

typedef __attribute__((ext_vector_type(8))) short s16x8;
typedef __attribute__((ext_vector_type(4))) short s16x4;
typedef __attribute__((ext_vector_type(4))) float f32x4;
typedef __attribute__((ext_vector_type(2))) unsigned int u32x2;

#define DEVINL __device__ __forceinline__

DEVINL float b2f(short x) {
  unsigned int u = ((unsigned int)(unsigned short)x) << 16;
  return __builtin_bit_cast(float, u);
}
DEVINL short f2b(float f) {
  unsigned int u = __builtin_bit_cast(unsigned int, f);
  unsigned int r = (u + 0x7fffu + ((u >> 16) & 1u)) >> 16;
  return (short)r;
}
DEVINL void gload16(const short* g, const short* l) {
  __builtin_amdgcn_global_load_lds(
      (const __attribute__((address_space(1))) void*)g,
      (__attribute__((address_space(3))) void*)l, 16, 0, 0);
}
DEVINL float max3f(float a, float b, float c) { return fmaxf(fmaxf(a, b), c); }

// ---------------- prep: f32 -> bf16 elementwise ----------------
__global__ __launch_bounds__(256) void conv_bf16(
    const float* __restrict__ src, short* __restrict__ dst)
{
  const size_t i = ((size_t)blockIdx.x * 256 + threadIdx.x) * 8;
  f32x4 a = *(const f32x4*)(src + i);
  f32x4 c = *(const f32x4*)(src + i + 4);
  s16x8 r;
#pragma unroll
  for (int u = 0; u < 4; ++u) { r[u] = f2b(a[u]); r[4 + u] = f2b(c[u]); }
  *(s16x8*)(dst + i) = r;
}

// ---------------- prep: W[k][n] f32 -> Wt[n][k] bf16 ----------------
__global__ __launch_bounds__(256) void transpose_w(
    const float* __restrict__ W0, const float* __restrict__ W1, const float* __restrict__ W2,
    short* __restrict__ T0, short* __restrict__ T1, short* __restrict__ T2)
{
  const float* W = blockIdx.z == 0 ? W0 : (blockIdx.z == 1 ? W1 : W2);
  short* T = blockIdx.z == 0 ? T0 : (blockIdx.z == 1 ? T1 : T2);
  __shared__ short t[32][33];
  const int k0 = blockIdx.x * 32, n0 = blockIdx.y * 32;
  const int a = threadIdx.x >> 3, cg = (threadIdx.x & 7) * 4;
  f32x4 v = *(const f32x4*)&W[(size_t)(k0 + a) * Dmc + n0 + cg];
#pragma unroll
  for (int u = 0; u < 4; ++u) t[a][cg + u] = f2b(v[u]);
  __syncthreads();
  s16x4 s;
#pragma unroll
  for (int u = 0; u < 4; ++u) s[u] = t[cg + u][a];
  *(s16x4*)&T[(size_t)(n0 + a) * Dmc + k0 + cg] = s;
}

// ---------------- merged projection GEMM, 128x128 tile (m97 geometry) ---------
__global__ __launch_bounds__(256) void gemm_fused(
    const short* __restrict__ X, const short* __restrict__ Wt,
    const float* __restrict__ b0, const float* __restrict__ b1, const float* __restrict__ b2,
    short* __restrict__ Y0, float scale0)
{
  __shared__ short lds[16384];
  char* ldsb = (char*)lds;
  const int tid = threadIdx.x, lane = tid & 63, wid = tid >> 6;
  const int gy = gridDim.y;

  const int rawd = blockIdx.x + 64 * blockIdx.y;
  const int wgid = (rawd & 7) * (gy * 8) + (rawd >> 3);
  const int mi0 = wgid / gy, ny = wgid - mi0 * gy;
  const int m0 = mi0 * 128;
  const int nch = ny / 6, ncol = (ny % 6) * 128;
  const int n0g = ny * 128;

  short* Y = Y0 + (size_t)nch * 6291456;
  const float* bias = nch == 0 ? b0 : (nch == 1 ? b1 : b2);
  const float scale = nch == 0 ? scale0 : 1.0f;

  const int lr = lane & 15, lq = lane >> 4;
  const int wm = (wid & 1) * 64, wn = (wid >> 1) * 64;

  const int l8 = lane >> 3, l7 = lane & 7;
  const int colsh = ((l7 * 16) ^ (l8 << 4)) >> 1;
  const short* Aptr[4];
  const short* Bptr[4];
#pragma unroll
  for (int i = 0; i < 4; ++i) {
    Aptr[i] = X  + (size_t)(m0  + wid * 32 + i * 8 + l8) * Dmc + colsh;
    Bptr[i] = Wt + (size_t)(n0g + wid * 32 + i * 8 + l8) * Dmc + colsh;
  }

  int arb[4][2], brb[4][2];
#pragma unroll
  for (int mi = 0; mi < 4; ++mi)
#pragma unroll
    for (int ks = 0; ks < 2; ++ks) {
      int row = wm + mi * 16 + lr;
      arb[mi][ks] = row * 128 + ((lq * 16 + ks * 64) ^ ((row & 7) << 4));
    }
#pragma unroll
  for (int ni = 0; ni < 4; ++ni)
#pragma unroll
    for (int ks = 0; ks < 2; ++ks) {
      int row = wn + ni * 16 + lr;
      brb[ni][ks] = 16384 + row * 128 + ((lq * 16 + ks * 64) ^ ((row & 7) << 4));
    }

  f32x4 acc[4][4] = {};

  for (int kt = 0; kt < 12; ++kt) {
    const int ko = kt * 64;
    if (kt) __syncthreads();
#pragma unroll
    for (int i = 0; i < 4; ++i) {
      gload16(Aptr[i] + ko, &lds[wid * 2048 + i * 512]);
      gload16(Bptr[i] + ko, &lds[8192 + wid * 2048 + i * 512]);
    }
    asm volatile("s_waitcnt vmcnt(0)" ::: "memory");
    __syncthreads();
#pragma unroll
    for (int ks = 0; ks < 2; ++ks) {
      s16x8 af[4], bf[4];
#pragma unroll
      for (int mi = 0; mi < 4; ++mi) af[mi] = *(const s16x8*)(ldsb + arb[mi][ks]);
#pragma unroll
      for (int ni = 0; ni < 4; ++ni) bf[ni] = *(const s16x8*)(ldsb + brb[ni][ks]);
#pragma unroll
      for (int mi = 0; mi < 4; ++mi)
#pragma unroll
        for (int ni = 0; ni < 4; ++ni)
          acc[mi][ni] = __builtin_amdgcn_mfma_f32_16x16x32_bf16(af[mi], bf[ni], acc[mi][ni], 0, 0, 0);
    }
  }

#pragma unroll
  for (int mi = 0; mi < 4; ++mi)
#pragma unroll
    for (int ni = 0; ni < 4; ++ni) {
      int col = ncol + wn + ni * 16 + lr;
      float bv_ = bias[col];
#pragma unroll
      for (int r = 0; r < 4; ++r) {
        int row = m0 + wm + mi * 16 + lq * 4 + r;
        Y[(size_t)row * Dmc + col] = f2b((acc[mi][ni][r] + bv_) * scale);
      }
    }
}

// ---------------- qg projection (exp2-domain scale) ----------------
__global__ __launch_bounds__(256) void qg_proj(
    const float* __restrict__ hs, const float* __restrict__ Wqg,
    const float* __restrict__ bqg, float* __restrict__ qg)
{
  const int row = blockIdx.x;
  const int b = row / Gc, i = row % Gc;
  const int tid = threadIdx.x;
  const int n = blockIdx.y * 128 + (tid & 127);
  const int half = tid >> 7;
  __shared__ float x[Dmc];
  __shared__ float part[128];
  for (int c = tid; c < Dmc; c += 256)
    x[c] = b2f(f2b(hs[((size_t)(b * Sc + i)) * Dmc + c]));
  __syncthreads();
  float acc = 0.f;
#pragma unroll 4
  for (int c = half * 384; c < half * 384 + 384; ++c)
    acc = fmaf(x[c], b2f(f2b(Wqg[(size_t)c * Dmc + n])), acc);
  if (half) part[tid & 127] = acc;
  __syncthreads();
  if (!half)
    qg[(size_t)row * Dmc + n] = (acc + part[tid] + bqg[n]) * SCALE2q;
}

// ---------------- MFMA banded attention v6: VALU diet on r9 structure ----------
__global__ __launch_bounds__(256) void local_attn_mfma(
    const short* __restrict__ q, const short* __restrict__ k,
    const short* __restrict__ v, float* __restrict__ out)
{
  const int raw = blockIdx.x + 64 * (blockIdx.y + 12 * blockIdx.z);
  const int swz = (raw & 7) * 192 + (raw >> 3);
  const int q0 = (swz & 63) * 64;
  const int h = (swz >> 6) % 12, b = swz / 768;
  const int tid = threadIdx.x, lane = tid & 63, wid = tid >> 6;

  __shared__ short Ks[4096];
  __shared__ short Vt[4096];
  __shared__ short Ps[4][1024];
  char* KsB = (char*)Ks;
  char* VtB = (char*)Vt;

  const int ql = lane & 15;
  const int lg = lane >> 4;
  const int qr = wid * 16 + ql;

  s16x8 qf[2];
  {
    const short* qp = q + ((size_t)(b * Sc + q0 + qr)) * Dmc + h * HDc + lg * 8;
    qf[0] = *(const s16x8*)qp;
    qf[1] = *(const s16x8*)(qp + 32);
  }

  f32x4 oacc[4] = {};
  float m_run = -INFINITY, l_run = 0.f;

  const int krow = tid >> 3, kcol16 = (tid & 7) * 16;
  const int vp = tid & 31, vo = tid >> 5;
  const size_t hoff = (size_t)h * HDc;
  const size_t brow = (size_t)b * Sc;

  // interior blocks: keys for chunks >=1 are strictly q0-272+col, in-range,
  // so staging pointers advance by a fixed 64-row stride (kills keyof VALU).
  const bool interior = (q0 >= 256) && (q0 <= Sc - 384);

  auto keyof = [&](int c) {
    int key = (c < Gc) ? c : q0 - 272 + c;
    return min(max(key, 0), Sc - 1);
  };

  const short *kp0, *kp1, *vp0, *vp1;
  s16x8 kreg0, kreg1, vreg0, vreg1;
  auto loadRegs = [&](int ch) {
    if (!interior || ch <= 1) {
      kp0 = k + (brow + keyof(ch * 64 + krow))       * Dmc + hoff + (kcol16 >> 1);
      kp1 = k + (brow + keyof(ch * 64 + 32 + krow))  * Dmc + hoff + (kcol16 >> 1);
      vp0 = v + (brow + keyof(ch * 64 + 2 * vp))      * Dmc + hoff + vo * 8;
      vp1 = v + (brow + keyof(ch * 64 + 2 * vp + 1))  * Dmc + hoff + vo * 8;
    } else {
      kp0 += 64 * Dmc; kp1 += 64 * Dmc; vp0 += 64 * Dmc; vp1 += 64 * Dmc;
    }
    kreg0 = *(const s16x8*)kp0;
    kreg1 = *(const s16x8*)kp1;
    vreg0 = *(const s16x8*)vp0;
    vreg1 = *(const s16x8*)vp1;
  };

  loadRegs(0);

  for (int ch = 0; ch < 10; ++ch) {
    __syncthreads();
    *(s16x8*)(KsB + krow * 128        + (kcol16 ^ ((krow & 7) << 4))) = kreg0;
    *(s16x8*)(KsB + (krow + 32) * 128 + (kcol16 ^ ((krow & 7) << 4))) = kreg1;
#pragma unroll
    for (int j = 0; j < 8; ++j) {
      int d = vo * 8 + j;
      unsigned int wrd = (unsigned int)(unsigned short)vreg0[j] |
                         ((unsigned int)(unsigned short)vreg1[j] << 16);
      *(unsigned int*)(VtB + d * 128 + ((4 * vp) ^ (j << 4))) = wrd;
    }
    if (ch < 9) loadRegs(ch + 1);
    __syncthreads();

    // chunk 9 (cols 576..639) is only live for wave 3 (qr>=48) — wave-uniform skip
    if (ch == 9 && wid != 3) continue;

    f32x4 sac[4] = {};
    __builtin_amdgcn_s_setprio(1);
#pragma unroll
    for (int kt = 0; kt < 4; ++kt) {
      int row = kt * 16 + ql;
#pragma unroll
      for (int sl = 0; sl < 2; ++sl) {
        s16x8 af = *(const s16x8*)(KsB + row * 128 + ((lg * 16 + sl * 64) ^ ((row & 7) << 4)));
        sac[kt] = __builtin_amdgcn_mfma_f32_16x16x32_bf16(af, qf[sl], sac[kt], 0, 0, 0);
      }
    }
    __builtin_amdgcn_s_setprio(0);

    bool needMask = (ch < 2) | (ch > 7) | (q0 < 272) | (q0 > Sc - 384);
    if (needMask) {
#pragma unroll
      for (int kt = 0; kt < 4; ++kt)
#pragma unroll
        for (int r = 0; r < 4; ++r) {
          int c = ch * 64 + kt * 16 + lg * 4 + r;
          if (c >= Gc) {
            float sv = sac[kt][r];
            int jj = c - Gc - qr;
            int kp2 = q0 - 272 + c;
            bool ok = (jj >= 0) & (jj <= 2 * Wc) & (kp2 >= 0) & (kp2 < Sc);
            sac[kt][r] = ok ? (sv + ((kp2 < Gc) ? NEG2c : 0.f)) : -INFINITY;
          }
        }
    }

    // max via v_max3 tree (T17)
    float t0 = max3f(sac[0][0], sac[0][1], sac[0][2]);
    float t1 = max3f(sac[0][3], sac[1][0], sac[1][1]);
    float t2 = max3f(sac[1][2], sac[1][3], sac[2][0]);
    float t3 = max3f(sac[2][1], sac[2][2], sac[2][3]);
    float t4 = max3f(sac[3][0], sac[3][1], sac[3][2]);
    float cm = fmaxf(max3f(t0, t1, t2), max3f(t3, t4, sac[3][3]));
    cm = fmaxf(cm, __shfl_xor(cm, 16));
    cm = fmaxf(cm, __shfl_xor(cm, 32));

    if (__all(cm <= m_run + 11.5f)) {
      float cl0 = 0.f, cl1 = 0.f, cl2 = 0.f, cl3 = 0.f;
#pragma unroll
      for (int kt = 0; kt < 4; ++kt) {
        float p0 = __builtin_amdgcn_exp2f(sac[kt][0] - m_run);
        float p1 = __builtin_amdgcn_exp2f(sac[kt][1] - m_run);
        float p2 = __builtin_amdgcn_exp2f(sac[kt][2] - m_run);
        float p3 = __builtin_amdgcn_exp2f(sac[kt][3] - m_run);
        sac[kt][0] = p0; sac[kt][1] = p1; sac[kt][2] = p2; sac[kt][3] = p3;
        cl0 += p0; cl1 += p1; cl2 += p2; cl3 += p3;
      }
      float cl = (cl0 + cl1) + (cl2 + cl3);
      cl += __shfl_xor(cl, 16);
      cl += __shfl_xor(cl, 32);
      l_run += cl;
    } else {
      float m_new = fmaxf(m_run, cm);
      float scale = __builtin_amdgcn_exp2f(m_run - m_new);
      float cl0 = 0.f, cl1 = 0.f, cl2 = 0.f, cl3 = 0.f;
#pragma unroll
      for (int kt = 0; kt < 4; ++kt) {
        float p0 = __builtin_amdgcn_exp2f(sac[kt][0] - m_new);
        float p1 = __builtin_amdgcn_exp2f(sac[kt][1] - m_new);
        float p2 = __builtin_amdgcn_exp2f(sac[kt][2] - m_new);
        float p3 = __builtin_amdgcn_exp2f(sac[kt][3] - m_new);
        sac[kt][0] = p0; sac[kt][1] = p1; sac[kt][2] = p2; sac[kt][3] = p3;
        cl0 += p0; cl1 += p1; cl2 += p2; cl3 += p3;
      }
      float cl = (cl0 + cl1) + (cl2 + cl3);
      cl += __shfl_xor(cl, 16);
      cl += __shfl_xor(cl, 32);
      l_run = l_run * scale + cl;
      m_run = m_new;
#pragma unroll
      for (int rr = 0; rr < 4; ++rr) {
        float os = __shfl(scale, lg * 4 + rr);
#pragma unroll
        for (int dt = 0; dt < 4; ++dt) oacc[dt][rr] *= os;
      }
    }

    char* PsB = (char*)Ps[wid];
#pragma unroll
    for (int kt = 0; kt < 4; ++kt) {
      u32x2 pw;
      asm("v_cvt_pk_bf16_f32 %0, %1, %2" : "=v"(pw.x) : "v"(sac[kt][0]), "v"(sac[kt][1]));
      asm("v_cvt_pk_bf16_f32 %0, %1, %2" : "=v"(pw.y) : "v"(sac[kt][2]), "v"(sac[kt][3]));
      *(u32x2*)(PsB + ql * 128 + ((kt * 32 + lg * 8) ^ ((ql & 7) << 4))) = pw;
    }
    s16x8 pf[2];
#pragma unroll
    for (int ks = 0; ks < 2; ++ks)
      pf[ks] = *(const s16x8*)(PsB + ql * 128 + ((ks * 64 + lg * 16) ^ ((ql & 7) << 4)));
    __builtin_amdgcn_s_setprio(1);
#pragma unroll
    for (int dt = 0; dt < 4; ++dt) {
      int d = dt * 16 + ql;
#pragma unroll
      for (int ks = 0; ks < 2; ++ks) {
        s16x8 vf = *(const s16x8*)(VtB + d * 128 + ((ks * 64 + lg * 16) ^ ((d & 7) << 4)));
        oacc[dt] = __builtin_amdgcn_mfma_f32_16x16x32_bf16(pf[ks], vf, oacc[dt], 0, 0, 0);
      }
    }
    __builtin_amdgcn_s_setprio(0);
  }

  float inv = 1.f / l_run;
#pragma unroll
  for (int rr = 0; rr < 4; ++rr) {
    float oi = __shfl(inv, lg * 4 + rr);
    int row = q0 + wid * 16 + lg * 4 + rr;
    float* op = out + ((size_t)(b * Sc + row)) * Dmc + h * HDc + ql;
#pragma unroll
    for (int dt = 0; dt < 4; ++dt)
      op[dt * 16] = oacc[dt][rr] * oi;
  }
}

// ---------------- global rows, split-K phase A ----------------
__global__ __launch_bounds__(256) void global_attn_part(
    const float* __restrict__ qg, const short* __restrict__ kg,
    const short* __restrict__ vg, float* __restrict__ pml, float* __restrict__ po)
{
  const int ch = blockIdx.x & (NCH - 1);
  const int i  = blockIdx.x >> 4;
  const int h = blockIdx.y, b = blockIdx.z;
  const int tid = threadIdx.x, lane = tid & 63, wid = tid >> 6;

  __shared__ float qrow[64];
  __shared__ float pls[CHK];
  __shared__ float red[8];
  __shared__ float osum[4][64];

  if (tid < 64) qrow[tid] = qg[(size_t)(b * Gc + i) * Dmc + h * HDc + tid];
  __syncthreads();

  const int sk = ch * CHK + tid;
  const s16x8* kr = (const s16x8*)(kg + ((size_t)(b * Sc + sk)) * Dmc + h * HDc);
  float acc = 0.f;
#pragma unroll
  for (int c = 0; c < 8; ++c) {
    s16x8 kv = kr[c];
#pragma unroll
    for (int u = 0; u < 8; ++u) acc = fmaf(qrow[c * 8 + u], b2f(kv[u]), acc);
  }

  float m = acc;
#pragma unroll
  for (int off = 32; off > 0; off >>= 1) m = fmaxf(m, __shfl_xor(m, off));
  if (lane == 0) red[wid] = m;
  __syncthreads();
  m = fmaxf(fmaxf(red[0], red[1]), fmaxf(red[2], red[3]));

  float p = __builtin_amdgcn_exp2f(acc - m);
  pls[tid] = p;
  float ls = p;
#pragma unroll
  for (int off = 32; off > 0; off >>= 1) ls += __shfl_xor(ls, off);
  if (lane == 0) red[4 + wid] = ls;
  __syncthreads();
  const float l = red[4] + red[5] + red[6] + red[7];

  const int jg = tid >> 3, db = (tid & 7) * 8;
  float o[8] = {};
  const short* vb2 = vg + ((size_t)(b * Sc + ch * CHK + jg * 8)) * Dmc + h * HDc + db;
#pragma unroll
  for (int jj = 0; jj < 8; ++jj) {
    float pw = pls[jg * 8 + jj];
    s16x8 vv = *(const s16x8*)(vb2 + (size_t)jj * Dmc);
#pragma unroll
    for (int u = 0; u < 8; ++u) o[u] = fmaf(pw, b2f(vv[u]), o[u]);
  }
#pragma unroll
  for (int mk = 8; mk <= 32; mk <<= 1)
#pragma unroll
    for (int u = 0; u < 8; ++u) o[u] += __shfl_xor(o[u], mk);
  if ((lane & 56) == 0) {
#pragma unroll
    for (int u = 0; u < 8; ++u) osum[wid][(lane & 7) * 8 + u] = o[u];
  }
  __syncthreads();

  const size_t slot = (((size_t)(b * Hc + h) * Gc + i) * NCH + ch);
  if (tid < 64)
    po[slot * 64 + tid] = osum[0][tid] + osum[1][tid] + osum[2][tid] + osum[3][tid];
  if (tid == 0) { pml[slot * 2] = m; pml[slot * 2 + 1] = l; }
}

// ---------------- global rows, split-K phase B ----------------
__global__ __launch_bounds__(64) void global_attn_comb(
    const float* __restrict__ pml, const float* __restrict__ po,
    float* __restrict__ out)
{
  const int i = blockIdx.x, h = blockIdx.y, b = blockIdx.z;
  const int d = threadIdx.x;
  const size_t base = ((size_t)(b * Hc + h) * Gc + i) * NCH;

  float m = -INFINITY;
#pragma unroll
  for (int ch = 0; ch < NCH; ++ch) m = fmaxf(m, pml[(base + ch) * 2]);
  float l = 0.f, o = 0.f;
#pragma unroll
  for (int ch = 0; ch < NCH; ++ch) {
    float wgt = __builtin_amdgcn_exp2f(pml[(base + ch) * 2] - m);
    l = fmaf(pml[(base + ch) * 2 + 1], wgt, l);
    o = fmaf(po[(base + ch) * 64 + d], wgt, o);
  }
  out[((size_t)(b * Sc + i)) * Dmc + h * HDc + d] = o / l;
}

extern "C" void kernel_launch(void* const* d_in, const int* in_sizes, int n_in,
                              void* d_out, int out_size, void* d_ws, size_t ws_size,
                              hipStream_t stream) {
  const float* hs  = (const float*)d_in[0];
  const float* Wq  = (const float*)d_in[1];
  const float* bq  = (const float*)d_in[2];
  const float* Wk  = (const float*)d_in[3];
  const float* bk  = (const float*)d_in[4];
  const float* Wv  = (const float*)d_in[5];
  const float* bv  = (const float*)d_in[6];
  const float* Wqg = (const float*)d_in[7];
  const float* bqg = (const float*)d_in[8];
  const float* Wkg = (const float*)d_in[9];
  const float* bkg = (const float*)d_in[10];
  const float* Wvg = (const float*)d_in[11];
  const float* bvg = (const float*)d_in[12];
  float* out = (float*)d_out;

  char* ws = (char*)d_ws;
  const size_t bufB = (size_t)Bc * Sc * Dmc * sizeof(short);   // 12,582,912
  short* hsb = (short*)(ws);
  short* s1  = (short*)(ws + bufB);        // q -> kg
  short* s2  = (short*)(ws + 2 * bufB);    // k -> vg
  short* s3  = (short*)(ws + 3 * bufB);    // v -> {qg,pml,po | Wt_kg,Wt_vg}

  short* wtA = (short*)d_out;              // Wt_{q,k,v} contiguous (d_out free pre-attn)
  short* wtB = wtA + (size_t)Dmc * Dmc;
  short* wtC = wtB + (size_t)Dmc * Dmc;
  float* qg  = (float*)(ws + 3 * bufB);
  float* pml = (float*)(ws + 3 * bufB + 98304);
  float* po  = (float*)(ws + 3 * bufB + 147456);
  short* wtD = (short*)(ws + 3 * bufB + (4u << 20));   // Wt_{kg,vg} contiguous
  short* wtE = wtD + (size_t)Dmc * Dmc;

  dim3 bb(256);
  conv_bf16<<<dim3(3072), bb, 0, stream>>>(hs, hsb);
  transpose_w<<<dim3(24, 24, 3), bb, 0, stream>>>(Wq, Wk, Wv, wtA, wtB, wtC);

  gemm_fused<<<dim3(64, 18), bb, 0, stream>>>(hsb, wtA, bq, bk, bv, s1, SCALE2q);

  local_attn_mfma<<<dim3(64, Hc, Bc), bb, 0, stream>>>(s1, s2, s3, out);

  transpose_w<<<dim3(24, 24, 2), bb, 0, stream>>>(Wkg, Wvg, Wvg, wtD, wtE, wtE);
  gemm_fused<<<dim3(64, 12), bb, 0, stream>>>(hsb, wtD, bkg, bvg, bvg, s1, 1.0f);

  qg_proj<<<dim3(Bc * Gc, Dmc / 128), bb, 0, stream>>>(hs, Wqg, bqg, qg);
  global_attn_part<<<dim3(Gc * NCH, Hc, Bc), bb, 0, stream>>>(qg, s1, s2, pml, po);
  global_attn_comb<<<dim3(Gc, Hc, Bc), dim3(64), 0, stream>>>(pml, po, out);
}

// Round 15
// 176.877 us; speedup vs baseline: 1.1764x; 1.0712x over previous
//
#include <hip/hip_runtime.h>

constexpr int Bc = 2, Sc = 4096, Dmc = 768, Hc = 12, HDc = 64, Wc = 256, Gc = 16;
constexpr int NCHG = 64;               // 64-key chunks for global rows (4096/64)
constexpr float LOG2E = 1.4426950408889634f;
constexpr float SCALE2q = 0.125f * LOG2E;   // q-scale in exp2 domain
constexpr float NEG2c = -10000.0f * LOG2E;  // mask addend in exp2 domain

typedef __attribute__((ext_vector_type(8))) short s16x8;
typedef __attribute__((ext_vector_type(4))) short s16x4;
typedef __attribute__((ext_vector_type(4))) float f32x4;
typedef __attribute__((ext_vector_type(2))) unsigned int u32x2;

#define DEVINL __device__ __forceinline__

DEVINL float b2f(short x) {
  unsigned int u = ((unsigned int)(unsigned short)x) << 16;
  return __builtin_bit_cast(float, u);
}
DEVINL short f2b(float f) {
  unsigned int u = __builtin_bit_cast(unsigned int, f);
  unsigned int r = (u + 0x7fffu + ((u >> 16) & 1u)) >> 16;
  return (short)r;
}
DEVINL void gload16(const short* g, const short* l) {
  __builtin_amdgcn_global_load_lds(
      (const __attribute__((address_space(1))) void*)g,
      (__attribute__((address_space(3))) void*)l, 16, 0, 0);
}
DEVINL float max3f(float a, float b, float c) { return fmaxf(fmaxf(a, b), c); }

// ---------------- prep: f32 -> bf16 elementwise ----------------
__global__ __launch_bounds__(256) void conv_bf16(
    const float* __restrict__ src, short* __restrict__ dst)
{
  const size_t i = ((size_t)blockIdx.x * 256 + threadIdx.x) * 8;
  f32x4 a = *(const f32x4*)(src + i);
  f32x4 c = *(const f32x4*)(src + i + 4);
  s16x8 r;
#pragma unroll
  for (int u = 0; u < 4; ++u) { r[u] = f2b(a[u]); r[4 + u] = f2b(c[u]); }
  *(s16x8*)(dst + i) = r;
}

// ---------------- prep: W[k][n] f32 -> Wt[n][k] bf16 ----------------
__global__ __launch_bounds__(256) void transpose_w(
    const float* __restrict__ W0, const float* __restrict__ W1, const float* __restrict__ W2,
    short* __restrict__ T0, short* __restrict__ T1, short* __restrict__ T2)
{
  const float* W = blockIdx.z == 0 ? W0 : (blockIdx.z == 1 ? W1 : W2);
  short* T = blockIdx.z == 0 ? T0 : (blockIdx.z == 1 ? T1 : T2);
  __shared__ short t[32][33];
  const int k0 = blockIdx.x * 32, n0 = blockIdx.y * 32;
  const int a = threadIdx.x >> 3, cg = (threadIdx.x & 7) * 4;
  f32x4 v = *(const f32x4*)&W[(size_t)(k0 + a) * Dmc + n0 + cg];
#pragma unroll
  for (int u = 0; u < 4; ++u) t[a][cg + u] = f2b(v[u]);
  __syncthreads();
  s16x4 s;
#pragma unroll
  for (int u = 0; u < 4; ++u) s[u] = t[cg + u][a];
  *(s16x4*)&T[(size_t)(n0 + a) * Dmc + k0 + cg] = s;
}

// ---------------- merged projection GEMM, 128x128 tile (r13-proven) ---------
__global__ __launch_bounds__(256) void gemm_fused(
    const short* __restrict__ X, const short* __restrict__ Wt,
    const float* __restrict__ b0, const float* __restrict__ b1, const float* __restrict__ b2,
    short* __restrict__ Y0, float scale0)
{
  __shared__ short lds[16384];
  char* ldsb = (char*)lds;
  const int tid = threadIdx.x, lane = tid & 63, wid = tid >> 6;
  const int gy = gridDim.y;

  const int rawd = blockIdx.x + 64 * blockIdx.y;
  const int wgid = (rawd & 7) * (gy * 8) + (rawd >> 3);
  const int mi0 = wgid / gy, ny = wgid - mi0 * gy;
  const int m0 = mi0 * 128;
  const int nch = ny / 6, ncol = (ny % 6) * 128;
  const int n0g = ny * 128;

  short* Y = Y0 + (size_t)nch * 6291456;
  const float* bias = nch == 0 ? b0 : (nch == 1 ? b1 : b2);
  const float scale = nch == 0 ? scale0 : 1.0f;

  const int lr = lane & 15, lq = lane >> 4;
  const int wm = (wid & 1) * 64, wn = (wid >> 1) * 64;

  const int l8 = lane >> 3, l7 = lane & 7;
  const int colsh = ((l7 * 16) ^ (l8 << 4)) >> 1;
  const short* Aptr[4];
  const short* Bptr[4];
#pragma unroll
  for (int i = 0; i < 4; ++i) {
    Aptr[i] = X  + (size_t)(m0  + wid * 32 + i * 8 + l8) * Dmc + colsh;
    Bptr[i] = Wt + (size_t)(n0g + wid * 32 + i * 8 + l8) * Dmc + colsh;
  }

  int arb[4][2], brb[4][2];
#pragma unroll
  for (int mi = 0; mi < 4; ++mi)
#pragma unroll
    for (int ks = 0; ks < 2; ++ks) {
      int row = wm + mi * 16 + lr;
      arb[mi][ks] = row * 128 + ((lq * 16 + ks * 64) ^ ((row & 7) << 4));
    }
#pragma unroll
  for (int ni = 0; ni < 4; ++ni)
#pragma unroll
    for (int ks = 0; ks < 2; ++ks) {
      int row = wn + ni * 16 + lr;
      brb[ni][ks] = 16384 + row * 128 + ((lq * 16 + ks * 64) ^ ((row & 7) << 4));
    }

  f32x4 acc[4][4] = {};

  for (int kt = 0; kt < 12; ++kt) {
    const int ko = kt * 64;
    if (kt) __syncthreads();
#pragma unroll
    for (int i = 0; i < 4; ++i) {
      gload16(Aptr[i] + ko, &lds[wid * 2048 + i * 512]);
      gload16(Bptr[i] + ko, &lds[8192 + wid * 2048 + i * 512]);
    }
    asm volatile("s_waitcnt vmcnt(0)" ::: "memory");
    __syncthreads();
#pragma unroll
    for (int ks = 0; ks < 2; ++ks) {
      s16x8 af[4], bf[4];
#pragma unroll
      for (int mi = 0; mi < 4; ++mi) af[mi] = *(const s16x8*)(ldsb + arb[mi][ks]);
#pragma unroll
      for (int ni = 0; ni < 4; ++ni) bf[ni] = *(const s16x8*)(ldsb + brb[ni][ks]);
#pragma unroll
      for (int mi = 0; mi < 4; ++mi)
#pragma unroll
        for (int ni = 0; ni < 4; ++ni)
          acc[mi][ni] = __builtin_amdgcn_mfma_f32_16x16x32_bf16(af[mi], bf[ni], acc[mi][ni], 0, 0, 0);
    }
  }

#pragma unroll
  for (int mi = 0; mi < 4; ++mi)
#pragma unroll
    for (int ni = 0; ni < 4; ++ni) {
      int col = ncol + wn + ni * 16 + lr;
      float bv_ = bias[col];
#pragma unroll
      for (int r = 0; r < 4; ++r) {
        int row = m0 + wm + mi * 16 + lq * 4 + r;
        Y[(size_t)row * Dmc + col] = f2b((acc[mi][ni][r] + bv_) * scale);
      }
    }
}

// ---------------- qg projection (exp2-domain scale), bf16 out ----------------
__global__ __launch_bounds__(256) void qg_proj(
    const float* __restrict__ hs, const float* __restrict__ Wqg,
    const float* __restrict__ bqg, short* __restrict__ qg)
{
  const int row = blockIdx.x;
  const int b = row / Gc, i = row % Gc;
  const int tid = threadIdx.x;
  const int n = blockIdx.y * 128 + (tid & 127);
  const int half = tid >> 7;
  __shared__ float x[Dmc];
  __shared__ float part[128];
  for (int c = tid; c < Dmc; c += 256)
    x[c] = b2f(f2b(hs[((size_t)(b * Sc + i)) * Dmc + c]));
  __syncthreads();
  float acc = 0.f;
#pragma unroll 4
  for (int c = half * 384; c < half * 384 + 384; ++c)
    acc = fmaf(x[c], b2f(f2b(Wqg[(size_t)c * Dmc + n])), acc);
  if (half) part[tid & 127] = acc;
  __syncthreads();
  if (!half)
    qg[(size_t)row * Dmc + n] = f2b((acc + part[tid] + bqg[n]) * SCALE2q);
}

// ---------------- MFMA banded attention v6 (r14-proven, unchanged) ----------
__global__ __launch_bounds__(256) void local_attn_mfma(
    const short* __restrict__ q, const short* __restrict__ k,
    const short* __restrict__ v, float* __restrict__ out)
{
  const int raw = blockIdx.x + 64 * (blockIdx.y + 12 * blockIdx.z);
  const int swz = (raw & 7) * 192 + (raw >> 3);
  const int q0 = (swz & 63) * 64;
  const int h = (swz >> 6) % 12, b = swz / 768;
  const int tid = threadIdx.x, lane = tid & 63, wid = tid >> 6;

  __shared__ short Ks[4096];
  __shared__ short Vt[4096];
  __shared__ short Ps[4][1024];
  char* KsB = (char*)Ks;
  char* VtB = (char*)Vt;

  const int ql = lane & 15;
  const int lg = lane >> 4;
  const int qr = wid * 16 + ql;

  s16x8 qf[2];
  {
    const short* qp = q + ((size_t)(b * Sc + q0 + qr)) * Dmc + h * HDc + lg * 8;
    qf[0] = *(const s16x8*)qp;
    qf[1] = *(const s16x8*)(qp + 32);
  }

  f32x4 oacc[4] = {};
  float m_run = -INFINITY, l_run = 0.f;

  const int krow = tid >> 3, kcol16 = (tid & 7) * 16;
  const int vp = tid & 31, vo = tid >> 5;
  const size_t hoff = (size_t)h * HDc;
  const size_t brow = (size_t)b * Sc;

  const bool interior = (q0 >= 256) && (q0 <= Sc - 384);

  auto keyof = [&](int c) {
    int key = (c < Gc) ? c : q0 - 272 + c;
    return min(max(key, 0), Sc - 1);
  };

  const short *kp0, *kp1, *vp0, *vp1;
  s16x8 kreg0, kreg1, vreg0, vreg1;
  auto loadRegs = [&](int ch) {
    if (!interior || ch <= 1) {
      kp0 = k + (brow + keyof(ch * 64 + krow))       * Dmc + hoff + (kcol16 >> 1);
      kp1 = k + (brow + keyof(ch * 64 + 32 + krow))  * Dmc + hoff + (kcol16 >> 1);
      vp0 = v + (brow + keyof(ch * 64 + 2 * vp))      * Dmc + hoff + vo * 8;
      vp1 = v + (brow + keyof(ch * 64 + 2 * vp + 1))  * Dmc + hoff + vo * 8;
    } else {
      kp0 += 64 * Dmc; kp1 += 64 * Dmc; vp0 += 64 * Dmc; vp1 += 64 * Dmc;
    }
    kreg0 = *(const s16x8*)kp0;
    kreg1 = *(const s16x8*)kp1;
    vreg0 = *(const s16x8*)vp0;
    vreg1 = *(const s16x8*)vp1;
  };

  loadRegs(0);

  for (int ch = 0; ch < 10; ++ch) {
    __syncthreads();
    *(s16x8*)(KsB + krow * 128        + (kcol16 ^ ((krow & 7) << 4))) = kreg0;
    *(s16x8*)(KsB + (krow + 32) * 128 + (kcol16 ^ ((krow & 7) << 4))) = kreg1;
#pragma unroll
    for (int j = 0; j < 8; ++j) {
      int d = vo * 8 + j;
      unsigned int wrd = (unsigned int)(unsigned short)vreg0[j] |
                         ((unsigned int)(unsigned short)vreg1[j] << 16);
      *(unsigned int*)(VtB + d * 128 + ((4 * vp) ^ (j << 4))) = wrd;
    }
    if (ch < 9) loadRegs(ch + 1);
    __syncthreads();

    if (ch == 9 && wid != 3) continue;

    f32x4 sac[4] = {};
    __builtin_amdgcn_s_setprio(1);
#pragma unroll
    for (int kt = 0; kt < 4; ++kt) {
      int row = kt * 16 + ql;
#pragma unroll
      for (int sl = 0; sl < 2; ++sl) {
        s16x8 af = *(const s16x8*)(KsB + row * 128 + ((lg * 16 + sl * 64) ^ ((row & 7) << 4)));
        sac[kt] = __builtin_amdgcn_mfma_f32_16x16x32_bf16(af, qf[sl], sac[kt], 0, 0, 0);
      }
    }
    __builtin_amdgcn_s_setprio(0);

    bool needMask = (ch < 2) | (ch > 7) | (q0 < 272) | (q0 > Sc - 384);
    if (needMask) {
#pragma unroll
      for (int kt = 0; kt < 4; ++kt)
#pragma unroll
        for (int r = 0; r < 4; ++r) {
          int c = ch * 64 + kt * 16 + lg * 4 + r;
          if (c >= Gc) {
            float sv = sac[kt][r];
            int jj = c - Gc - qr;
            int kp2 = q0 - 272 + c;
            bool ok = (jj >= 0) & (jj <= 2 * Wc) & (kp2 >= 0) & (kp2 < Sc);
            sac[kt][r] = ok ? (sv + ((kp2 < Gc) ? NEG2c : 0.f)) : -INFINITY;
          }
        }
    }

    float t0 = max3f(sac[0][0], sac[0][1], sac[0][2]);
    float t1 = max3f(sac[0][3], sac[1][0], sac[1][1]);
    float t2 = max3f(sac[1][2], sac[1][3], sac[2][0]);
    float t3 = max3f(sac[2][1], sac[2][2], sac[2][3]);
    float t4 = max3f(sac[3][0], sac[3][1], sac[3][2]);
    float cm = fmaxf(max3f(t0, t1, t2), max3f(t3, t4, sac[3][3]));
    cm = fmaxf(cm, __shfl_xor(cm, 16));
    cm = fmaxf(cm, __shfl_xor(cm, 32));

    if (__all(cm <= m_run + 11.5f)) {
      float cl0 = 0.f, cl1 = 0.f, cl2 = 0.f, cl3 = 0.f;
#pragma unroll
      for (int kt = 0; kt < 4; ++kt) {
        float p0 = __builtin_amdgcn_exp2f(sac[kt][0] - m_run);
        float p1 = __builtin_amdgcn_exp2f(sac[kt][1] - m_run);
        float p2 = __builtin_amdgcn_exp2f(sac[kt][2] - m_run);
        float p3 = __builtin_amdgcn_exp2f(sac[kt][3] - m_run);
        sac[kt][0] = p0; sac[kt][1] = p1; sac[kt][2] = p2; sac[kt][3] = p3;
        cl0 += p0; cl1 += p1; cl2 += p2; cl3 += p3;
      }
      float cl = (cl0 + cl1) + (cl2 + cl3);
      cl += __shfl_xor(cl, 16);
      cl += __shfl_xor(cl, 32);
      l_run += cl;
    } else {
      float m_new = fmaxf(m_run, cm);
      float scale = __builtin_amdgcn_exp2f(m_run - m_new);
      float cl0 = 0.f, cl1 = 0.f, cl2 = 0.f, cl3 = 0.f;
#pragma unroll
      for (int kt = 0; kt < 4; ++kt) {
        float p0 = __builtin_amdgcn_exp2f(sac[kt][0] - m_new);
        float p1 = __builtin_amdgcn_exp2f(sac[kt][1] - m_new);
        float p2 = __builtin_amdgcn_exp2f(sac[kt][2] - m_new);
        float p3 = __builtin_amdgcn_exp2f(sac[kt][3] - m_new);
        sac[kt][0] = p0; sac[kt][1] = p1; sac[kt][2] = p2; sac[kt][3] = p3;
        cl0 += p0; cl1 += p1; cl2 += p2; cl3 += p3;
      }
      float cl = (cl0 + cl1) + (cl2 + cl3);
      cl += __shfl_xor(cl, 16);
      cl += __shfl_xor(cl, 32);
      l_run = l_run * scale + cl;
      m_run = m_new;
#pragma unroll
      for (int rr = 0; rr < 4; ++rr) {
        float os = __shfl(scale, lg * 4 + rr);
#pragma unroll
        for (int dt = 0; dt < 4; ++dt) oacc[dt][rr] *= os;
      }
    }

    char* PsB = (char*)Ps[wid];
#pragma unroll
    for (int kt = 0; kt < 4; ++kt) {
      u32x2 pw;
      asm("v_cvt_pk_bf16_f32 %0, %1, %2" : "=v"(pw.x) : "v"(sac[kt][0]), "v"(sac[kt][1]));
      asm("v_cvt_pk_bf16_f32 %0, %1, %2" : "=v"(pw.y) : "v"(sac[kt][2]), "v"(sac[kt][3]));
      *(u32x2*)(PsB + ql * 128 + ((kt * 32 + lg * 8) ^ ((ql & 7) << 4))) = pw;
    }
    s16x8 pf[2];
#pragma unroll
    for (int ks = 0; ks < 2; ++ks)
      pf[ks] = *(const s16x8*)(PsB + ql * 128 + ((ks * 64 + lg * 16) ^ ((ql & 7) << 4)));
    __builtin_amdgcn_s_setprio(1);
#pragma unroll
    for (int dt = 0; dt < 4; ++dt) {
      int d = dt * 16 + ql;
#pragma unroll
      for (int ks = 0; ks < 2; ++ks) {
        s16x8 vf = *(const s16x8*)(VtB + d * 128 + ((ks * 64 + lg * 16) ^ ((d & 7) << 4)));
        oacc[dt] = __builtin_amdgcn_mfma_f32_16x16x32_bf16(pf[ks], vf, oacc[dt], 0, 0, 0);
      }
    }
    __builtin_amdgcn_s_setprio(0);
  }

  float inv = 1.f / l_run;
#pragma unroll
  for (int rr = 0; rr < 4; ++rr) {
    float oi = __shfl(inv, lg * 4 + rr);
    int row = q0 + wid * 16 + lg * 4 + rr;
    float* op = out + ((size_t)(b * Sc + row)) * Dmc + h * HDc + ql;
#pragma unroll
    for (int dt = 0; dt < 4; ++dt)
      op[dt * 16] = oacc[dt][rr] * oi;
  }
}

// ---------------- global rows, MFMA split-K phase A: 1 wave per 64-key chunk ----
// Partial (m, l, O[16][64]) per (b,h,chunk). Single wave: no barriers needed.
__global__ __launch_bounds__(64) void global_attn_part_mfma(
    const short* __restrict__ qg, const short* __restrict__ kg,
    const short* __restrict__ vg, float* __restrict__ pml, float* __restrict__ po)
{
  const int ch = blockIdx.x, h = blockIdx.y, b = blockIdx.z;
  const int lane = threadIdx.x;

  __shared__ short Ks[4096];      // [64 key][64 d], XOR-swizzled
  __shared__ short Vt[4096];      // [64 d][64 key], XOR-swizzled pair-packed
  __shared__ short Ps[1024];      // [16 q][64 k]
  char* KsB = (char*)Ks;
  char* VtB = (char*)Vt;

  const int ql = lane & 15;
  const int lg = lane >> 4;

  // Q fragment: B-frag, col = ql = global row i, k over d
  s16x8 qf[2];
  {
    const short* qp = qg + ((size_t)(b * Gc + ql)) * Dmc + h * HDc + lg * 8;
    qf[0] = *(const s16x8*)qp;
    qf[1] = *(const s16x8*)(qp + 32);
  }

  const size_t hoff = (size_t)h * HDc;
  const size_t brow = (size_t)b * Sc;
  const int key0 = ch * 64;

  // stage K: 8 iterations, rows krow+8*rr, byte slice kcol16
  const int krow = lane >> 3, kcol16 = (lane & 7) * 16;
#pragma unroll
  for (int rr = 0; rr < 8; ++rr) {
    int row = krow + rr * 8;
    s16x8 kv = *(const s16x8*)(kg + (brow + key0 + row) * Dmc + hoff + (kcol16 >> 1));
    *(s16x8*)(KsB + row * 128 + (kcol16 ^ ((row & 7) << 4))) = kv;
  }
  // stage V^T: pair-packed; 4 iterations over d-octets
  const int vp = lane & 31, vo0 = lane >> 5;
#pragma unroll
  for (int oo = 0; oo < 4; ++oo) {
    int vo = vo0 + oo * 2;
    s16x8 v0 = *(const s16x8*)(vg + (brow + key0 + 2 * vp)     * Dmc + hoff + vo * 8);
    s16x8 v1 = *(const s16x8*)(vg + (brow + key0 + 2 * vp + 1) * Dmc + hoff + vo * 8);
#pragma unroll
    for (int j = 0; j < 8; ++j) {
      int d = vo * 8 + j;
      unsigned int wrd = (unsigned int)(unsigned short)v0[j] |
                         ((unsigned int)(unsigned short)v1[j] << 16);
      *(unsigned int*)(VtB + d * 128 + ((4 * vp) ^ (j << 4))) = wrd;
    }
  }

  // QK^T: sac[kt] = S^T[k=kt*16+lg*4+r][q=ql]
  f32x4 sac[4] = {};
#pragma unroll
  for (int kt = 0; kt < 4; ++kt) {
    int row = kt * 16 + ql;
#pragma unroll
    for (int sl = 0; sl < 2; ++sl) {
      s16x8 af = *(const s16x8*)(KsB + row * 128 + ((lg * 16 + sl * 64) ^ ((row & 7) << 4)));
      sac[kt] = __builtin_amdgcn_mfma_f32_16x16x32_bf16(af, qf[sl], sac[kt], 0, 0, 0);
    }
  }

  // single-shot softmax partial (no mask: all 4096 keys valid for global rows)
  float t0 = max3f(sac[0][0], sac[0][1], sac[0][2]);
  float t1 = max3f(sac[0][3], sac[1][0], sac[1][1]);
  float t2 = max3f(sac[1][2], sac[1][3], sac[2][0]);
  float t3 = max3f(sac[2][1], sac[2][2], sac[2][3]);
  float t4 = max3f(sac[3][0], sac[3][1], sac[3][2]);
  float m = fmaxf(max3f(t0, t1, t2), max3f(t3, t4, sac[3][3]));
  m = fmaxf(m, __shfl_xor(m, 16));
  m = fmaxf(m, __shfl_xor(m, 32));

  float cl = 0.f;
#pragma unroll
  for (int kt = 0; kt < 4; ++kt)
#pragma unroll
    for (int r = 0; r < 4; ++r) {
      float p = __builtin_amdgcn_exp2f(sac[kt][r] - m);
      sac[kt][r] = p;
      cl += p;
    }
  cl += __shfl_xor(cl, 16);
  cl += __shfl_xor(cl, 32);

  // P relayout via Ps (r9-proven pattern)
#pragma unroll
  for (int kt = 0; kt < 4; ++kt) {
    u32x2 pw;
    asm("v_cvt_pk_bf16_f32 %0, %1, %2" : "=v"(pw.x) : "v"(sac[kt][0]), "v"(sac[kt][1]));
    asm("v_cvt_pk_bf16_f32 %0, %1, %2" : "=v"(pw.y) : "v"(sac[kt][2]), "v"(sac[kt][3]));
    *(u32x2*)((char*)Ps + ql * 128 + ((kt * 32 + lg * 8) ^ ((ql & 7) << 4))) = pw;
  }
  s16x8 pf[2];
#pragma unroll
  for (int ks = 0; ks < 2; ++ks)
    pf[ks] = *(const s16x8*)((char*)Ps + ql * 128 + ((ks * 64 + lg * 16) ^ ((ql & 7) << 4)));

  f32x4 oacc[4] = {};
#pragma unroll
  for (int dt = 0; dt < 4; ++dt) {
    int d = dt * 16 + ql;
#pragma unroll
    for (int ks = 0; ks < 2; ++ks) {
      s16x8 vf = *(const s16x8*)(VtB + d * 128 + ((ks * 64 + lg * 16) ^ ((d & 7) << 4)));
      oacc[dt] = __builtin_amdgcn_mfma_f32_16x16x32_bf16(pf[ks], vf, oacc[dt], 0, 0, 0);
    }
  }

  // write partial: slot = ((b*Hc+h)*NCHG + ch); O[q][d] un-normalized
  const size_t slot = ((size_t)(b * Hc + h) * NCHG + ch);
  float* pob = po + slot * 1024;
#pragma unroll
  for (int rr = 0; rr < 4; ++rr) {
    int qrow = lg * 4 + rr;
#pragma unroll
    for (int dt = 0; dt < 4; ++dt)
      pob[qrow * 64 + dt * 16 + ql] = oacc[dt][rr];
  }
  if (lg == 0) {
    pml[(slot * 16 + ql) * 2]     = m;
    pml[(slot * 16 + ql) * 2 + 1] = cl;
  }
}

// ---------------- global rows, split-K phase B: combine 64 partials ----------
__global__ __launch_bounds__(64) void global_attn_comb(
    const float* __restrict__ pml, const float* __restrict__ po,
    float* __restrict__ out)
{
  const int i = blockIdx.x, h = blockIdx.y, b = blockIdx.z;
  const int d = threadIdx.x;
  const size_t base = (size_t)(b * Hc + h) * NCHG;

  float m = -INFINITY;
#pragma unroll 8
  for (int ch = 0; ch < NCHG; ++ch) m = fmaxf(m, pml[((base + ch) * 16 + i) * 2]);
  float l = 0.f, o = 0.f;
#pragma unroll 8
  for (int ch = 0; ch < NCHG; ++ch) {
    float wgt = __builtin_amdgcn_exp2f(pml[((base + ch) * 16 + i) * 2] - m);
    l = fmaf(pml[((base + ch) * 16 + i) * 2 + 1], wgt, l);
    o = fmaf(po[(base + ch) * 1024 + i * 64 + d], wgt, o);
  }
  out[((size_t)(b * Sc + i)) * Dmc + h * HDc + d] = o / l;
}

extern "C" void kernel_launch(void* const* d_in, const int* in_sizes, int n_in,
                              void* d_out, int out_size, void* d_ws, size_t ws_size,
                              hipStream_t stream) {
  const float* hs  = (const float*)d_in[0];
  const float* Wq  = (const float*)d_in[1];
  const float* bq  = (const float*)d_in[2];
  const float* Wk  = (const float*)d_in[3];
  const float* bk  = (const float*)d_in[4];
  const float* Wv  = (const float*)d_in[5];
  const float* bv  = (const float*)d_in[6];
  const float* Wqg = (const float*)d_in[7];
  const float* bqg = (const float*)d_in[8];
  const float* Wkg = (const float*)d_in[9];
  const float* bkg = (const float*)d_in[10];
  const float* Wvg = (const float*)d_in[11];
  const float* bvg = (const float*)d_in[12];
  float* out = (float*)d_out;

  char* ws = (char*)d_ws;
  const size_t bufB = (size_t)Bc * Sc * Dmc * sizeof(short);   // 12,582,912
  short* hsb = (short*)(ws);
  short* s1  = (short*)(ws + bufB);        // q -> kg
  short* s2  = (short*)(ws + 2 * bufB);    // k -> vg
  short* s3  = (short*)(ws + 3 * bufB);    // v -> {qg,pml,po | Wt_kg,Wt_vg}

  short* wtA = (short*)d_out;              // Wt_{q,k,v} contiguous (d_out free pre-attn)
  short* wtB = wtA + (size_t)Dmc * Dmc;
  short* wtC = wtB + (size_t)Dmc * Dmc;
  short* qgb = (short*)(ws + 3 * bufB);                 // 49,152 B (bf16)
  float* pml = (float*)(ws + 3 * bufB + 65536);         // 196,608 B
  float* po  = (float*)(ws + 3 * bufB + (1u << 20));    // 6.29 MB (overlaps wtD region;
                                                        //  written only after gemm_small)
  short* wtD = (short*)(ws + 3 * bufB + (8u << 20));    // Wt_kg (1.18 MB)
  short* wtE = wtD + (size_t)Dmc * Dmc;                 // Wt_vg -> ends at 11.9 MB < 12.58

  dim3 bb(256);
  conv_bf16<<<dim3(3072), bb, 0, stream>>>(hs, hsb);
  transpose_w<<<dim3(24, 24, 3), bb, 0, stream>>>(Wq, Wk, Wv, wtA, wtB, wtC);

  gemm_fused<<<dim3(64, 18), bb, 0, stream>>>(hsb, wtA, bq, bk, bv, s1, SCALE2q);

  local_attn_mfma<<<dim3(64, Hc, Bc), bb, 0, stream>>>(s1, s2, s3, out);

  transpose_w<<<dim3(24, 24, 2), bb, 0, stream>>>(Wkg, Wvg, Wvg, wtD, wtE, wtE);
  gemm_fused<<<dim3(64, 12), bb, 0, stream>>>(hsb, wtD, bkg, bvg, bvg, s1, 1.0f);

  qg_proj<<<dim3(Bc * Gc, Dmc / 128), bb, 0, stream>>>(hs, Wqg, bqg, qgb);
  global_attn_part_mfma<<<dim3(NCHG, Hc, Bc), dim3(64), 0, stream>>>(qgb, s1, s2, pml, po);
  global_attn_comb<<<dim3(Gc, Hc, Bc), dim3(64), 0, stream>>>(pml, po, out);
}

// Round 19
// 174.687 us; speedup vs baseline: 1.1912x; 1.0125x over previous
//
#include <hip/hip_runtime.h>

constexpr int Bc = 2, Sc = 4096, Dmc = 768, Hc = 12, HDc = 64, Wc = 256, Gc = 16;
constexpr int NCHG = 64;               // 64-key chunks for global rows (4096/64)
constexpr float LOG2E = 1.4426950408889634f;
constexpr float SCALE2q = 0.125f * LOG2E;   // q-scale in exp2 domain
constexpr float NEG2c = -10000.0f * LOG2E;  // mask addend in exp2 domain
constexpr size_t BUFE = 6291456;       // elements per [8192][768] bf16 buffer

typedef __attribute__((ext_vector_type(8))) short s16x8;
typedef __attribute__((ext_vector_type(4))) short s16x4;
typedef __attribute__((ext_vector_type(4))) float f32x4;
typedef __attribute__((ext_vector_type(2))) unsigned int u32x2;

#define DEVINL __device__ __forceinline__

DEVINL float b2f(short x) {
  unsigned int u = ((unsigned int)(unsigned short)x) << 16;
  return __builtin_bit_cast(float, u);
}
DEVINL short f2b(float f) {
  unsigned int u = __builtin_bit_cast(unsigned int, f);
  unsigned int r = (u + 0x7fffu + ((u >> 16) & 1u)) >> 16;
  return (short)r;
}
DEVINL void gload16(const short* g, const short* l) {
  __builtin_amdgcn_global_load_lds(
      (const __attribute__((address_space(1))) void*)g,
      (__attribute__((address_space(3))) void*)l, 16, 0, 0);
}
DEVINL float max3f(float a, float b, float c) { return fmaxf(fmaxf(a, b), c); }

// ---------------- prep: f32 -> bf16 elementwise ----------------
__global__ __launch_bounds__(256) void conv_bf16(
    const float* __restrict__ src, short* __restrict__ dst)
{
  const size_t i = ((size_t)blockIdx.x * 256 + threadIdx.x) * 8;
  f32x4 a = *(const f32x4*)(src + i);
  f32x4 c = *(const f32x4*)(src + i + 4);
  s16x8 r;
#pragma unroll
  for (int u = 0; u < 4; ++u) { r[u] = f2b(a[u]); r[4 + u] = f2b(c[u]); }
  *(s16x8*)(dst + i) = r;
}

// ---------------- prep: up-to-five W[k][n] f32 -> Wt[n][k] bf16 --------------
__global__ __launch_bounds__(256) void transpose_w5(
    const float* __restrict__ W0, const float* __restrict__ W1,
    const float* __restrict__ W2, const float* __restrict__ W3,
    const float* __restrict__ W4, short* __restrict__ Tbase)
{
  const int z = blockIdx.z;
  const float* W = z == 0 ? W0 : (z == 1 ? W1 : (z == 2 ? W2 : (z == 3 ? W3 : W4)));
  short* T = Tbase + (size_t)z * Dmc * Dmc;
  __shared__ short t[32][33];
  const int k0 = blockIdx.x * 32, n0 = blockIdx.y * 32;
  const int a = threadIdx.x >> 3, cg = (threadIdx.x & 7) * 4;
  f32x4 v = *(const f32x4*)&W[(size_t)(k0 + a) * Dmc + n0 + cg];
#pragma unroll
  for (int u = 0; u < 4; ++u) t[a][cg + u] = f2b(v[u]);
  __syncthreads();
  s16x4 s;
#pragma unroll
  for (int u = 0; u < 4; ++u) s[u] = t[cg + u][a];
  *(s16x4*)&T[(size_t)(n0 + a) * Dmc + k0 + cg] = s;
}

// ---------------- merged projection GEMM, 128x128 tile ----------------
// nch = ny/6: nch<3 -> Yws + nch*BUFE; nch>=3 -> Yout + (nch-3)*BUFE.
__global__ __launch_bounds__(256) void gemm_all(
    const short* __restrict__ X, const short* __restrict__ Wt,
    const float* __restrict__ b0, const float* __restrict__ b1,
    const float* __restrict__ b2, const float* __restrict__ b3,
    const float* __restrict__ b4,
    short* __restrict__ Yws, short* __restrict__ Yout, float scale0)
{
  __shared__ short lds[16384];
  char* ldsb = (char*)lds;
  const int tid = threadIdx.x, lane = tid & 63, wid = tid >> 6;
  const int gy = gridDim.y;

  const int rawd = blockIdx.x + 64 * blockIdx.y;
  const int wgid = (rawd & 7) * (gy * 8) + (rawd >> 3);
  const int mi0 = wgid / gy, ny = wgid - mi0 * gy;
  const int m0 = mi0 * 128;
  const int nch = ny / 6, ncol = (ny % 6) * 128;
  const int n0g = ny * 128;

  short* Y = (nch < 3) ? (Yws + (size_t)nch * BUFE) : (Yout + (size_t)(nch - 3) * BUFE);
  const float* bias = nch == 0 ? b0 : (nch == 1 ? b1 : (nch == 2 ? b2 : (nch == 3 ? b3 : b4)));
  const float scale = nch == 0 ? scale0 : 1.0f;

  const int lr = lane & 15, lq = lane >> 4;
  const int wm = (wid & 1) * 64, wn = (wid >> 1) * 64;

  const int l8 = lane >> 3, l7 = lane & 7;
  const int colsh = ((l7 * 16) ^ (l8 << 4)) >> 1;
  const short* Aptr[4];
  const short* Bptr[4];
#pragma unroll
  for (int i = 0; i < 4; ++i) {
    Aptr[i] = X  + (size_t)(m0  + wid * 32 + i * 8 + l8) * Dmc + colsh;
    Bptr[i] = Wt + (size_t)(n0g + wid * 32 + i * 8 + l8) * Dmc + colsh;
  }

  int arb[4][2], brb[4][2];
#pragma unroll
  for (int mi = 0; mi < 4; ++mi)
#pragma unroll
    for (int ks = 0; ks < 2; ++ks) {
      int row = wm + mi * 16 + lr;
      arb[mi][ks] = row * 128 + ((lq * 16 + ks * 64) ^ ((row & 7) << 4));
    }
#pragma unroll
  for (int ni = 0; ni < 4; ++ni)
#pragma unroll
    for (int ks = 0; ks < 2; ++ks) {
      int row = wn + ni * 16 + lr;
      brb[ni][ks] = 16384 + row * 128 + ((lq * 16 + ks * 64) ^ ((row & 7) << 4));
    }

  f32x4 acc[4][4] = {};

  for (int kt = 0; kt < 12; ++kt) {
    const int ko = kt * 64;
    if (kt) __syncthreads();
#pragma unroll
    for (int i = 0; i < 4; ++i) {
      gload16(Aptr[i] + ko, &lds[wid * 2048 + i * 512]);
      gload16(Bptr[i] + ko, &lds[8192 + wid * 2048 + i * 512]);
    }
    asm volatile("s_waitcnt vmcnt(0)" ::: "memory");
    __syncthreads();
#pragma unroll
    for (int ks = 0; ks < 2; ++ks) {
      s16x8 af[4], bf[4];
#pragma unroll
      for (int mi = 0; mi < 4; ++mi) af[mi] = *(const s16x8*)(ldsb + arb[mi][ks]);
#pragma unroll
      for (int ni = 0; ni < 4; ++ni) bf[ni] = *(const s16x8*)(ldsb + brb[ni][ks]);
#pragma unroll
      for (int mi = 0; mi < 4; ++mi)
#pragma unroll
        for (int ni = 0; ni < 4; ++ni)
          acc[mi][ni] = __builtin_amdgcn_mfma_f32_16x16x32_bf16(af[mi], bf[ni], acc[mi][ni], 0, 0, 0);
    }
  }

#pragma unroll
  for (int mi = 0; mi < 4; ++mi)
#pragma unroll
    for (int ni = 0; ni < 4; ++ni) {
      int col = ncol + wn + ni * 16 + lr;
      float bv_ = bias[col];
#pragma unroll
      for (int r = 0; r < 4; ++r) {
        int row = m0 + wm + mi * 16 + lq * 4 + r;
        Y[(size_t)row * Dmc + col] = f2b((acc[mi][ni][r] + bv_) * scale);
      }
    }
}

// ---------------- qg projection (exp2-domain scale), bf16 out ----------------
__global__ __launch_bounds__(256) void qg_proj(
    const float* __restrict__ hs, const float* __restrict__ Wqg,
    const float* __restrict__ bqg, short* __restrict__ qg)
{
  const int row = blockIdx.x;
  const int b = row / Gc, i = row % Gc;
  const int tid = threadIdx.x;
  const int n = blockIdx.y * 128 + (tid & 127);
  const int half = tid >> 7;
  __shared__ float x[Dmc];
  __shared__ float part[128];
  for (int c = tid; c < Dmc; c += 256)
    x[c] = b2f(f2b(hs[((size_t)(b * Sc + i)) * Dmc + c]));
  __syncthreads();
  float acc = 0.f;
#pragma unroll 4
  for (int c = half * 384; c < half * 384 + 384; ++c)
    acc = fmaf(x[c], b2f(f2b(Wqg[(size_t)c * Dmc + n])), acc);
  if (half) part[tid & 127] = acc;
  __syncthreads();
  if (!half)
    qg[(size_t)row * Dmc + n] = f2b((acc + part[tid] + bqg[n]) * SCALE2q);
}

// ---------------- MFMA banded attention v6 (r14-proven, unchanged) ----------
__global__ __launch_bounds__(256) void local_attn_mfma(
    const short* __restrict__ q, const short* __restrict__ k,
    const short* __restrict__ v, float* __restrict__ out)
{
  const int raw = blockIdx.x + 64 * (blockIdx.y + 12 * blockIdx.z);
  const int swz = (raw & 7) * 192 + (raw >> 3);
  const int q0 = (swz & 63) * 64;
  const int h = (swz >> 6) % 12, b = swz / 768;
  const int tid = threadIdx.x, lane = tid & 63, wid = tid >> 6;

  __shared__ short Ks[4096];
  __shared__ short Vt[4096];
  __shared__ short Ps[4][1024];
  char* KsB = (char*)Ks;
  char* VtB = (char*)Vt;

  const int ql = lane & 15;
  const int lg = lane >> 4;
  const int qr = wid * 16 + ql;

  s16x8 qf[2];
  {
    const short* qp = q + ((size_t)(b * Sc + q0 + qr)) * Dmc + h * HDc + lg * 8;
    qf[0] = *(const s16x8*)qp;
    qf[1] = *(const s16x8*)(qp + 32);
  }

  f32x4 oacc[4] = {};
  float m_run = -INFINITY, l_run = 0.f;

  const int krow = tid >> 3, kcol16 = (tid & 7) * 16;
  const int vp = tid & 31, vo = tid >> 5;
  const size_t hoff = (size_t)h * HDc;
  const size_t brow = (size_t)b * Sc;

  const bool interior = (q0 >= 256) && (q0 <= Sc - 384);

  auto keyof = [&](int c) {
    int key = (c < Gc) ? c : q0 - 272 + c;
    return min(max(key, 0), Sc - 1);
  };

  const short *kp0, *kp1, *vp0, *vp1;
  s16x8 kreg0, kreg1, vreg0, vreg1;
  auto loadRegs = [&](int ch) {
    if (!interior || ch <= 1) {
      kp0 = k + (brow + keyof(ch * 64 + krow))       * Dmc + hoff + (kcol16 >> 1);
      kp1 = k + (brow + keyof(ch * 64 + 32 + krow))  * Dmc + hoff + (kcol16 >> 1);
      vp0 = v + (brow + keyof(ch * 64 + 2 * vp))      * Dmc + hoff + vo * 8;
      vp1 = v + (brow + keyof(ch * 64 + 2 * vp + 1))  * Dmc + hoff + vo * 8;
    } else {
      kp0 += 64 * Dmc; kp1 += 64 * Dmc; vp0 += 64 * Dmc; vp1 += 64 * Dmc;
    }
    kreg0 = *(const s16x8*)kp0;
    kreg1 = *(const s16x8*)kp1;
    vreg0 = *(const s16x8*)vp0;
    vreg1 = *(const s16x8*)vp1;
  };

  loadRegs(0);

  for (int ch = 0; ch < 10; ++ch) {
    __syncthreads();
    *(s16x8*)(KsB + krow * 128        + (kcol16 ^ ((krow & 7) << 4))) = kreg0;
    *(s16x8*)(KsB + (krow + 32) * 128 + (kcol16 ^ ((krow & 7) << 4))) = kreg1;
#pragma unroll
    for (int j = 0; j < 8; ++j) {
      int d = vo * 8 + j;
      unsigned int wrd = (unsigned int)(unsigned short)vreg0[j] |
                         ((unsigned int)(unsigned short)vreg1[j] << 16);
      *(unsigned int*)(VtB + d * 128 + ((4 * vp) ^ (j << 4))) = wrd;
    }
    if (ch < 9) loadRegs(ch + 1);
    __syncthreads();

    if (ch == 9 && wid != 3) continue;

    f32x4 sac[4] = {};
    __builtin_amdgcn_s_setprio(1);
#pragma unroll
    for (int kt = 0; kt < 4; ++kt) {
      int row = kt * 16 + ql;
#pragma unroll
      for (int sl = 0; sl < 2; ++sl) {
        s16x8 af = *(const s16x8*)(KsB + row * 128 + ((lg * 16 + sl * 64) ^ ((row & 7) << 4)));
        sac[kt] = __builtin_amdgcn_mfma_f32_16x16x32_bf16(af, qf[sl], sac[kt], 0, 0, 0);
      }
    }
    __builtin_amdgcn_s_setprio(0);

    bool needMask = (ch < 2) | (ch > 7) | (q0 < 272) | (q0 > Sc - 384);
    if (needMask) {
#pragma unroll
      for (int kt = 0; kt < 4; ++kt)
#pragma unroll
        for (int r = 0; r < 4; ++r) {
          int c = ch * 64 + kt * 16 + lg * 4 + r;
          if (c >= Gc) {
            float sv = sac[kt][r];
            int jj = c - Gc - qr;
            int kp2 = q0 - 272 + c;
            bool ok = (jj >= 0) & (jj <= 2 * Wc) & (kp2 >= 0) & (kp2 < Sc);
            sac[kt][r] = ok ? (sv + ((kp2 < Gc) ? NEG2c : 0.f)) : -INFINITY;
          }
        }
    }

    float t0 = max3f(sac[0][0], sac[0][1], sac[0][2]);
    float t1 = max3f(sac[0][3], sac[1][0], sac[1][1]);
    float t2 = max3f(sac[1][2], sac[1][3], sac[2][0]);
    float t3 = max3f(sac[2][1], sac[2][2], sac[2][3]);
    float t4 = max3f(sac[3][0], sac[3][1], sac[3][2]);
    float cm = fmaxf(max3f(t0, t1, t2), max3f(t3, t4, sac[3][3]));
    cm = fmaxf(cm, __shfl_xor(cm, 16));
    cm = fmaxf(cm, __shfl_xor(cm, 32));

    if (__all(cm <= m_run + 11.5f)) {
      float cl0 = 0.f, cl1 = 0.f, cl2 = 0.f, cl3 = 0.f;
#pragma unroll
      for (int kt = 0; kt < 4; ++kt) {
        float p0 = __builtin_amdgcn_exp2f(sac[kt][0] - m_run);
        float p1 = __builtin_amdgcn_exp2f(sac[kt][1] - m_run);
        float p2 = __builtin_amdgcn_exp2f(sac[kt][2] - m_run);
        float p3 = __builtin_amdgcn_exp2f(sac[kt][3] - m_run);
        sac[kt][0] = p0; sac[kt][1] = p1; sac[kt][2] = p2; sac[kt][3] = p3;
        cl0 += p0; cl1 += p1; cl2 += p2; cl3 += p3;
      }
      float cl = (cl0 + cl1) + (cl2 + cl3);
      cl += __shfl_xor(cl, 16);
      cl += __shfl_xor(cl, 32);
      l_run += cl;
    } else {
      float m_new = fmaxf(m_run, cm);
      float scale = __builtin_amdgcn_exp2f(m_run - m_new);
      float cl0 = 0.f, cl1 = 0.f, cl2 = 0.f, cl3 = 0.f;
#pragma unroll
      for (int kt = 0; kt < 4; ++kt) {
        float p0 = __builtin_amdgcn_exp2f(sac[kt][0] - m_new);
        float p1 = __builtin_amdgcn_exp2f(sac[kt][1] - m_new);
        float p2 = __builtin_amdgcn_exp2f(sac[kt][2] - m_new);
        float p3 = __builtin_amdgcn_exp2f(sac[kt][3] - m_new);
        sac[kt][0] = p0; sac[kt][1] = p1; sac[kt][2] = p2; sac[kt][3] = p3;
        cl0 += p0; cl1 += p1; cl2 += p2; cl3 += p3;
      }
      float cl = (cl0 + cl1) + (cl2 + cl3);
      cl += __shfl_xor(cl, 16);
      cl += __shfl_xor(cl, 32);
      l_run = l_run * scale + cl;
      m_run = m_new;
#pragma unroll
      for (int rr = 0; rr < 4; ++rr) {
        float os = __shfl(scale, lg * 4 + rr);
#pragma unroll
        for (int dt = 0; dt < 4; ++dt) oacc[dt][rr] *= os;
      }
    }

    char* PsB = (char*)Ps[wid];
#pragma unroll
    for (int kt = 0; kt < 4; ++kt) {
      u32x2 pw;
      asm("v_cvt_pk_bf16_f32 %0, %1, %2" : "=v"(pw.x) : "v"(sac[kt][0]), "v"(sac[kt][1]));
      asm("v_cvt_pk_bf16_f32 %0, %1, %2" : "=v"(pw.y) : "v"(sac[kt][2]), "v"(sac[kt][3]));
      *(u32x2*)(PsB + ql * 128 + ((kt * 32 + lg * 8) ^ ((ql & 7) << 4))) = pw;
    }
    s16x8 pf[2];
#pragma unroll
    for (int ks = 0; ks < 2; ++ks)
      pf[ks] = *(const s16x8*)(PsB + ql * 128 + ((ks * 64 + lg * 16) ^ ((ql & 7) << 4)));
    __builtin_amdgcn_s_setprio(1);
#pragma unroll
    for (int dt = 0; dt < 4; ++dt) {
      int d = dt * 16 + ql;
#pragma unroll
      for (int ks = 0; ks < 2; ++ks) {
        s16x8 vf = *(const s16x8*)(VtB + d * 128 + ((ks * 64 + lg * 16) ^ ((d & 7) << 4)));
        oacc[dt] = __builtin_amdgcn_mfma_f32_16x16x32_bf16(pf[ks], vf, oacc[dt], 0, 0, 0);
      }
    }
    __builtin_amdgcn_s_setprio(0);
  }

  float inv = 1.f / l_run;
#pragma unroll
  for (int rr = 0; rr < 4; ++rr) {
    float oi = __shfl(inv, lg * 4 + rr);
    int row = q0 + wid * 16 + lg * 4 + rr;
    float* op = out + ((size_t)(b * Sc + row)) * Dmc + h * HDc + ql;
#pragma unroll
    for (int dt = 0; dt < 4; ++dt)
      op[dt * 16] = oacc[dt][rr] * oi;
  }
}

// ---------------- global rows, MFMA split-K phase A (r15-proven) ----------
__global__ __launch_bounds__(64) void global_attn_part_mfma(
    const short* __restrict__ qg, const short* __restrict__ kg,
    const short* __restrict__ vg, float* __restrict__ pml, float* __restrict__ po)
{
  const int ch = blockIdx.x, h = blockIdx.y, b = blockIdx.z;
  const int lane = threadIdx.x;

  __shared__ short Ks[4096];
  __shared__ short Vt[4096];
  __shared__ short Ps[1024];
  char* KsB = (char*)Ks;
  char* VtB = (char*)Vt;

  const int ql = lane & 15;
  const int lg = lane >> 4;

  s16x8 qf[2];
  {
    const short* qp = qg + ((size_t)(b * Gc + ql)) * Dmc + h * HDc + lg * 8;
    qf[0] = *(const s16x8*)qp;
    qf[1] = *(const s16x8*)(qp + 32);
  }

  const size_t hoff = (size_t)h * HDc;
  const size_t brow = (size_t)b * Sc;
  const int key0 = ch * 64;

  const int krow = lane >> 3, kcol16 = (lane & 7) * 16;
#pragma unroll
  for (int rr = 0; rr < 8; ++rr) {
    int row = krow + rr * 8;
    s16x8 kv = *(const s16x8*)(kg + (brow + key0 + row) * Dmc + hoff + (kcol16 >> 1));
    *(s16x8*)(KsB + row * 128 + (kcol16 ^ ((row & 7) << 4))) = kv;
  }
  const int vp = lane & 31, vo0 = lane >> 5;
#pragma unroll
  for (int oo = 0; oo < 4; ++oo) {
    int vo = vo0 + oo * 2;
    s16x8 v0 = *(const s16x8*)(vg + (brow + key0 + 2 * vp)     * Dmc + hoff + vo * 8);
    s16x8 v1 = *(const s16x8*)(vg + (brow + key0 + 2 * vp + 1) * Dmc + hoff + vo * 8);
#pragma unroll
    for (int j = 0; j < 8; ++j) {
      int d = vo * 8 + j;
      unsigned int wrd = (unsigned int)(unsigned short)v0[j] |
                         ((unsigned int)(unsigned short)v1[j] << 16);
      *(unsigned int*)(VtB + d * 128 + ((4 * vp) ^ (j << 4))) = wrd;
    }
  }

  f32x4 sac[4] = {};
#pragma unroll
  for (int kt = 0; kt < 4; ++kt) {
    int row = kt * 16 + ql;
#pragma unroll
    for (int sl = 0; sl < 2; ++sl) {
      s16x8 af = *(const s16x8*)(KsB + row * 128 + ((lg * 16 + sl * 64) ^ ((row & 7) << 4)));
      sac[kt] = __builtin_amdgcn_mfma_f32_16x16x32_bf16(af, qf[sl], sac[kt], 0, 0, 0);
    }
  }

  float t0 = max3f(sac[0][0], sac[0][1], sac[0][2]);
  float t1 = max3f(sac[0][3], sac[1][0], sac[1][1]);
  float t2 = max3f(sac[1][2], sac[1][3], sac[2][0]);
  float t3 = max3f(sac[2][1], sac[2][2], sac[2][3]);
  float t4 = max3f(sac[3][0], sac[3][1], sac[3][2]);
  float m = fmaxf(max3f(t0, t1, t2), max3f(t3, t4, sac[3][3]));
  m = fmaxf(m, __shfl_xor(m, 16));
  m = fmaxf(m, __shfl_xor(m, 32));

  float cl = 0.f;
#pragma unroll
  for (int kt = 0; kt < 4; ++kt)
#pragma unroll
    for (int r = 0; r < 4; ++r) {
      float p = __builtin_amdgcn_exp2f(sac[kt][r] - m);
      sac[kt][r] = p;
      cl += p;
    }
  cl += __shfl_xor(cl, 16);
  cl += __shfl_xor(cl, 32);

#pragma unroll
  for (int kt = 0; kt < 4; ++kt) {
    u32x2 pw;
    asm("v_cvt_pk_bf16_f32 %0, %1, %2" : "=v"(pw.x) : "v"(sac[kt][0]), "v"(sac[kt][1]));
    asm("v_cvt_pk_bf16_f32 %0, %1, %2" : "=v"(pw.y) : "v"(sac[kt][2]), "v"(sac[kt][3]));
    *(u32x2*)((char*)Ps + ql * 128 + ((kt * 32 + lg * 8) ^ ((ql & 7) << 4))) = pw;
  }
  s16x8 pf[2];
#pragma unroll
  for (int ks = 0; ks < 2; ++ks)
    pf[ks] = *(const s16x8*)((char*)Ps + ql * 128 + ((ks * 64 + lg * 16) ^ ((ql & 7) << 4)));

  f32x4 oacc[4] = {};
#pragma unroll
  for (int dt = 0; dt < 4; ++dt) {
    int d = dt * 16 + ql;
#pragma unroll
    for (int ks = 0; ks < 2; ++ks) {
      s16x8 vf = *(const s16x8*)(VtB + d * 128 + ((ks * 64 + lg * 16) ^ ((d & 7) << 4)));
      oacc[dt] = __builtin_amdgcn_mfma_f32_16x16x32_bf16(pf[ks], vf, oacc[dt], 0, 0, 0);
    }
  }

  const size_t slot = ((size_t)(b * Hc + h) * NCHG + ch);
  float* pob = po + slot * 1024;
#pragma unroll
  for (int rr = 0; rr < 4; ++rr) {
    int qrow = lg * 4 + rr;
#pragma unroll
    for (int dt = 0; dt < 4; ++dt)
      pob[qrow * 64 + dt * 16 + ql] = oacc[dt][rr];
  }
  if (lg == 0) {
    pml[(slot * 16 + ql) * 2]     = m;
    pml[(slot * 16 + ql) * 2 + 1] = cl;
  }
}

// ---------------- global rows, split-K phase B: combine 64 partials ----------
__global__ __launch_bounds__(64) void global_attn_comb(
    const float* __restrict__ pml, const float* __restrict__ po,
    float* __restrict__ out)
{
  const int i = blockIdx.x, h = blockIdx.y, b = blockIdx.z;
  const int d = threadIdx.x;
  const size_t base = (size_t)(b * Hc + h) * NCHG;

  float m = -INFINITY;
#pragma unroll 8
  for (int ch = 0; ch < NCHG; ++ch) m = fmaxf(m, pml[((base + ch) * 16 + i) * 2]);
  float l = 0.f, o = 0.f;
#pragma unroll 8
  for (int ch = 0; ch < NCHG; ++ch) {
    float wgt = __builtin_amdgcn_exp2f(pml[((base + ch) * 16 + i) * 2] - m);
    l = fmaf(pml[((base + ch) * 16 + i) * 2 + 1], wgt, l);
    o = fmaf(po[(base + ch) * 1024 + i * 64 + d], wgt, o);
  }
  out[((size_t)(b * Sc + i)) * Dmc + h * HDc + d] = o / l;
}

extern "C" void kernel_launch(void* const* d_in, const int* in_sizes, int n_in,
                              void* d_out, int out_size, void* d_ws, size_t ws_size,
                              hipStream_t stream) {
  const float* hs  = (const float*)d_in[0];
  const float* Wq  = (const float*)d_in[1];
  const float* bq  = (const float*)d_in[2];
  const float* Wk  = (const float*)d_in[3];
  const float* bk  = (const float*)d_in[4];
  const float* Wv  = (const float*)d_in[5];
  const float* bv  = (const float*)d_in[6];
  const float* Wqg = (const float*)d_in[7];
  const float* bqg = (const float*)d_in[8];
  const float* Wkg = (const float*)d_in[9];
  const float* bkg = (const float*)d_in[10];
  const float* Wvg = (const float*)d_in[11];
  const float* bvg = (const float*)d_in[12];
  float* out = (float*)d_out;

  char* ws = (char*)d_ws;
  const size_t bufB = (size_t)Bc * Sc * Dmc * sizeof(short);   // 12,582,912
  const size_t wt5B = 5ull * Dmc * Dmc * sizeof(short);        // 5,898,240
  short* hsb = (short*)(ws);
  short* qb  = (short*)(ws + bufB);       // q, k at +BUFE, v at +2*BUFE (ends 4*bufB)

  dim3 bb(256);

  if (ws_size >= 4 * bufB + wt5B) {
    // ---------- merged path: wt5 beyond the 4th buffer; scratch in dead hsb ----
    short* wt5 = (short*)(ws + 4 * bufB);
    short* qgb = (short*)(ws);                    // hsb dead after gemm_all
    float* pml = (float*)(ws + 262144);
    float* po  = (float*)(ws + (1u << 20));
    short* kgb = (short*)d_out;                   // kg | vg fill d_out exactly
    short* vgb = kgb + BUFE;

    conv_bf16<<<dim3(3072), bb, 0, stream>>>(hs, hsb);
    transpose_w5<<<dim3(24, 24, 5), bb, 0, stream>>>(Wq, Wk, Wv, Wkg, Wvg, wt5);
    gemm_all<<<dim3(64, 30), bb, 0, stream>>>(hsb, wt5, bq, bk, bv, bkg, bvg,
                                              qb, kgb, SCALE2q);
    qg_proj<<<dim3(Bc * Gc, Dmc / 128), bb, 0, stream>>>(hs, Wqg, bqg, qgb);
    global_attn_part_mfma<<<dim3(NCHG, Hc, Bc), dim3(64), 0, stream>>>(qgb, kgb, vgb, pml, po);
    local_attn_mfma<<<dim3(64, Hc, Bc), bb, 0, stream>>>(qb, qb + BUFE, qb + 2 * BUFE, out);
    global_attn_comb<<<dim3(Gc, Hc, Bc), dim3(64), 0, stream>>>(pml, po, out);
  } else {
    // ---------- fallback: exact r15 sequence (proven 176.9 us) ----------
    short* wtA = (short*)d_out;                   // Wt_{q,k,v} (d_out free pre-attn)
    short* qgb = (short*)(ws + 3 * bufB);         // v-region, dead after local_attn
    float* pml = (float*)(ws + 3 * bufB + 262144);
    float* po  = (float*)(ws + 3 * bufB + (1u << 20));
    short* wtD = (short*)(ws + 3 * bufB + (8u << 20));
    short* kgb = qb;                              // kg over q, vg over k (post-attn)
    short* vgb = qb + BUFE;

    conv_bf16<<<dim3(3072), bb, 0, stream>>>(hs, hsb);
    transpose_w5<<<dim3(24, 24, 3), bb, 0, stream>>>(Wq, Wk, Wv, Wv, Wv, wtA);
    gemm_all<<<dim3(64, 18), bb, 0, stream>>>(hsb, wtA, bq, bk, bv, bv, bv,
                                              qb, qb, SCALE2q);
    local_attn_mfma<<<dim3(64, Hc, Bc), bb, 0, stream>>>(qb, qb + BUFE, qb + 2 * BUFE, out);
    transpose_w5<<<dim3(24, 24, 2), bb, 0, stream>>>(Wkg, Wvg, Wvg, Wvg, Wvg, wtD);
    gemm_all<<<dim3(64, 12), bb, 0, stream>>>(hsb, wtD, bkg, bvg, bvg, bvg, bvg,
                                              kgb, kgb, 1.0f);
    qg_proj<<<dim3(Bc * Gc, Dmc / 128), bb, 0, stream>>>(hs, Wqg, bqg, qgb);
    global_attn_part_mfma<<<dim3(NCHG, Hc, Bc), dim3(64), 0, stream>>>(qgb, kgb, vgb, pml, po);
    global_attn_comb<<<dim3(Gc, Hc, Bc), dim3(64), 0, stream>>>(pml, po, out);
  }
}

// Round 20
// 160.134 us; speedup vs baseline: 1.2994x; 1.0909x over previous
//
#include <hip/hip_runtime.h>

constexpr int Bc = 2, Sc = 4096, Dmc = 768, Hc = 12, HDc = 64, Wc = 256, Gc = 16;
constexpr int NCHG = 64;               // 64-key chunks for global rows (4096/64)
constexpr float LOG2E = 1.4426950408889634f;
constexpr float SCALE2q = 0.125f * LOG2E;   // q-scale in exp2 domain
constexpr float NEG2c = -10000.0f * LOG2E;  // mask addend in exp2 domain
constexpr size_t BUFE = 6291456;       // elements per [8192][768] bf16 buffer

typedef __attribute__((ext_vector_type(8))) short s16x8;
typedef __attribute__((ext_vector_type(4))) short s16x4;
typedef __attribute__((ext_vector_type(4))) float f32x4;
typedef __attribute__((ext_vector_type(2))) unsigned int u32x2;

#define DEVINL __device__ __forceinline__

DEVINL float b2f(short x) {
  unsigned int u = ((unsigned int)(unsigned short)x) << 16;
  return __builtin_bit_cast(float, u);
}
DEVINL short f2b(float f) {
  unsigned int u = __builtin_bit_cast(unsigned int, f);
  unsigned int r = (u + 0x7fffu + ((u >> 16) & 1u)) >> 16;
  return (short)r;
}
DEVINL void gload16(const short* g, const short* l) {
  __builtin_amdgcn_global_load_lds(
      (const __attribute__((address_space(1))) void*)g,
      (__attribute__((address_space(3))) void*)l, 16, 0, 0);
}
DEVINL float max3f(float a, float b, float c) { return fmaxf(fmaxf(a, b), c); }

// ---------------- fused prep: hs f32->bf16 (blocks 0..3071) + 5x W transpose ----
__global__ __launch_bounds__(256) void prep_fused(
    const float* __restrict__ src, short* __restrict__ dst,
    const float* __restrict__ W0, const float* __restrict__ W1,
    const float* __restrict__ W2, const float* __restrict__ W3,
    const float* __restrict__ W4, short* __restrict__ Tbase)
{
  __shared__ short t[32][33];
  const int bx = blockIdx.x;
  if (bx < 3072) {
    const size_t i = ((size_t)bx * 256 + threadIdx.x) * 8;
    f32x4 a = *(const f32x4*)(src + i);
    f32x4 c = *(const f32x4*)(src + i + 4);
    s16x8 r;
#pragma unroll
    for (int u = 0; u < 4; ++u) { r[u] = f2b(a[u]); r[4 + u] = f2b(c[u]); }
    *(s16x8*)(dst + i) = r;
    return;
  }
  const int tz = bx - 3072;
  const int z = tz / 576, rem = tz % 576;
  const float* W = z == 0 ? W0 : (z == 1 ? W1 : (z == 2 ? W2 : (z == 3 ? W3 : W4)));
  short* T = Tbase + (size_t)z * Dmc * Dmc;
  const int k0 = (rem / 24) * 32, n0 = (rem % 24) * 32;
  const int a = threadIdx.x >> 3, cg = (threadIdx.x & 7) * 4;
  f32x4 v = *(const f32x4*)&W[(size_t)(k0 + a) * Dmc + n0 + cg];
#pragma unroll
  for (int u = 0; u < 4; ++u) t[a][cg + u] = f2b(v[u]);
  __syncthreads();
  s16x4 s;
#pragma unroll
  for (int u = 0; u < 4; ++u) s[u] = t[cg + u][a];
  *(s16x4*)&T[(size_t)(n0 + a) * Dmc + k0 + cg] = s;
}

// ---------------- standalone transpose (fallback path) ----------------
__global__ __launch_bounds__(256) void transpose_w5(
    const float* __restrict__ W0, const float* __restrict__ W1,
    const float* __restrict__ W2, const float* __restrict__ W3,
    const float* __restrict__ W4, short* __restrict__ Tbase)
{
  const int z = blockIdx.z;
  const float* W = z == 0 ? W0 : (z == 1 ? W1 : (z == 2 ? W2 : (z == 3 ? W3 : W4)));
  short* T = Tbase + (size_t)z * Dmc * Dmc;
  __shared__ short t[32][33];
  const int k0 = blockIdx.x * 32, n0 = blockIdx.y * 32;
  const int a = threadIdx.x >> 3, cg = (threadIdx.x & 7) * 4;
  f32x4 v = *(const f32x4*)&W[(size_t)(k0 + a) * Dmc + n0 + cg];
#pragma unroll
  for (int u = 0; u < 4; ++u) t[a][cg + u] = f2b(v[u]);
  __syncthreads();
  s16x4 s;
#pragma unroll
  for (int u = 0; u < 4; ++u) s[u] = t[cg + u][a];
  *(s16x4*)&T[(size_t)(n0 + a) * Dmc + k0 + cg] = s;
}

__global__ __launch_bounds__(256) void conv_bf16(
    const float* __restrict__ src, short* __restrict__ dst)
{
  const size_t i = ((size_t)blockIdx.x * 256 + threadIdx.x) * 8;
  f32x4 a = *(const f32x4*)(src + i);
  f32x4 c = *(const f32x4*)(src + i + 4);
  s16x8 r;
#pragma unroll
  for (int u = 0; u < 4; ++u) { r[u] = f2b(a[u]); r[4 + u] = f2b(c[u]); }
  *(s16x8*)(dst + i) = r;
}

// ---------------- merged projection GEMM, 128x128 tile ----------------
__global__ __launch_bounds__(256) void gemm_all(
    const short* __restrict__ X, const short* __restrict__ Wt,
    const float* __restrict__ b0, const float* __restrict__ b1,
    const float* __restrict__ b2, const float* __restrict__ b3,
    const float* __restrict__ b4,
    short* __restrict__ Yws, short* __restrict__ Yout, float scale0)
{
  __shared__ short lds[16384];
  char* ldsb = (char*)lds;
  const int tid = threadIdx.x, lane = tid & 63, wid = tid >> 6;
  const int gy = gridDim.y;

  const int rawd = blockIdx.x + 64 * blockIdx.y;
  const int wgid = (rawd & 7) * (gy * 8) + (rawd >> 3);
  const int mi0 = wgid / gy, ny = wgid - mi0 * gy;
  const int m0 = mi0 * 128;
  const int nch = ny / 6, ncol = (ny % 6) * 128;
  const int n0g = ny * 128;

  short* Y = (nch < 3) ? (Yws + (size_t)nch * BUFE) : (Yout + (size_t)(nch - 3) * BUFE);
  const float* bias = nch == 0 ? b0 : (nch == 1 ? b1 : (nch == 2 ? b2 : (nch == 3 ? b3 : b4)));
  const float scale = nch == 0 ? scale0 : 1.0f;

  const int lr = lane & 15, lq = lane >> 4;
  const int wm = (wid & 1) * 64, wn = (wid >> 1) * 64;

  const int l8 = lane >> 3, l7 = lane & 7;
  const int colsh = ((l7 * 16) ^ (l8 << 4)) >> 1;
  const short* Aptr[4];
  const short* Bptr[4];
#pragma unroll
  for (int i = 0; i < 4; ++i) {
    Aptr[i] = X  + (size_t)(m0  + wid * 32 + i * 8 + l8) * Dmc + colsh;
    Bptr[i] = Wt + (size_t)(n0g + wid * 32 + i * 8 + l8) * Dmc + colsh;
  }

  int arb[4][2], brb[4][2];
#pragma unroll
  for (int mi = 0; mi < 4; ++mi)
#pragma unroll
    for (int ks = 0; ks < 2; ++ks) {
      int row = wm + mi * 16 + lr;
      arb[mi][ks] = row * 128 + ((lq * 16 + ks * 64) ^ ((row & 7) << 4));
    }
#pragma unroll
  for (int ni = 0; ni < 4; ++ni)
#pragma unroll
    for (int ks = 0; ks < 2; ++ks) {
      int row = wn + ni * 16 + lr;
      brb[ni][ks] = 16384 + row * 128 + ((lq * 16 + ks * 64) ^ ((row & 7) << 4));
    }

  f32x4 acc[4][4] = {};

  for (int kt = 0; kt < 12; ++kt) {
    const int ko = kt * 64;
    if (kt) __syncthreads();
#pragma unroll
    for (int i = 0; i < 4; ++i) {
      gload16(Aptr[i] + ko, &lds[wid * 2048 + i * 512]);
      gload16(Bptr[i] + ko, &lds[8192 + wid * 2048 + i * 512]);
    }
    asm volatile("s_waitcnt vmcnt(0)" ::: "memory");
    __syncthreads();
#pragma unroll
    for (int ks = 0; ks < 2; ++ks) {
      s16x8 af[4], bf[4];
#pragma unroll
      for (int mi = 0; mi < 4; ++mi) af[mi] = *(const s16x8*)(ldsb + arb[mi][ks]);
#pragma unroll
      for (int ni = 0; ni < 4; ++ni) bf[ni] = *(const s16x8*)(ldsb + brb[ni][ks]);
#pragma unroll
      for (int mi = 0; mi < 4; ++mi)
#pragma unroll
        for (int ni = 0; ni < 4; ++ni)
          acc[mi][ni] = __builtin_amdgcn_mfma_f32_16x16x32_bf16(af[mi], bf[ni], acc[mi][ni], 0, 0, 0);
    }
  }

#pragma unroll
  for (int mi = 0; mi < 4; ++mi)
#pragma unroll
    for (int ni = 0; ni < 4; ++ni) {
      int col = ncol + wn + ni * 16 + lr;
      float bv_ = bias[col];
#pragma unroll
      for (int r = 0; r < 4; ++r) {
        int row = m0 + wm + mi * 16 + lq * 4 + r;
        Y[(size_t)row * Dmc + col] = f2b((acc[mi][ni][r] + bv_) * scale);
      }
    }
}

// ---------------- qg projection v2: 4-way K-split, grid (32, 12) ----------------
__global__ __launch_bounds__(256) void qg_proj(
    const float* __restrict__ hs, const float* __restrict__ Wqg,
    const float* __restrict__ bqg, short* __restrict__ qg)
{
  const int row = blockIdx.x;           // b*G + i
  const int b = row >> 4, i = row & 15;
  const int tid = threadIdx.x;
  const int n = blockIdx.y * 64 + (tid & 63);
  const int qtr = tid >> 6;             // 0..3 c-quarters
  __shared__ float x[Dmc];
  __shared__ float part[3][64];
  for (int c = tid; c < Dmc; c += 256)
    x[c] = b2f(f2b(hs[((size_t)(b * Sc + i)) * Dmc + c]));
  __syncthreads();
  float acc = 0.f;
#pragma unroll 4
  for (int c = qtr * 192; c < qtr * 192 + 192; ++c)
    acc = fmaf(x[c], b2f(f2b(Wqg[(size_t)c * Dmc + n])), acc);
  if (qtr) part[qtr - 1][tid & 63] = acc;
  __syncthreads();
  if (!qtr)
    qg[(size_t)row * Dmc + n] =
        f2b((acc + part[0][tid] + part[1][tid] + part[2][tid] + bqg[n]) * SCALE2q);
}

// ---------------- MFMA banded attention v6 (r14-proven, unchanged) ----------
__global__ __launch_bounds__(256) void local_attn_mfma(
    const short* __restrict__ q, const short* __restrict__ k,
    const short* __restrict__ v, float* __restrict__ out)
{
  const int raw = blockIdx.x + 64 * (blockIdx.y + 12 * blockIdx.z);
  const int swz = (raw & 7) * 192 + (raw >> 3);
  const int q0 = (swz & 63) * 64;
  const int h = (swz >> 6) % 12, b = swz / 768;
  const int tid = threadIdx.x, lane = tid & 63, wid = tid >> 6;

  __shared__ short Ks[4096];
  __shared__ short Vt[4096];
  __shared__ short Ps[4][1024];
  char* KsB = (char*)Ks;
  char* VtB = (char*)Vt;

  const int ql = lane & 15;
  const int lg = lane >> 4;
  const int qr = wid * 16 + ql;

  s16x8 qf[2];
  {
    const short* qp = q + ((size_t)(b * Sc + q0 + qr)) * Dmc + h * HDc + lg * 8;
    qf[0] = *(const s16x8*)qp;
    qf[1] = *(const s16x8*)(qp + 32);
  }

  f32x4 oacc[4] = {};
  float m_run = -INFINITY, l_run = 0.f;

  const int krow = tid >> 3, kcol16 = (tid & 7) * 16;
  const int vp = tid & 31, vo = tid >> 5;
  const size_t hoff = (size_t)h * HDc;
  const size_t brow = (size_t)b * Sc;

  const bool interior = (q0 >= 256) && (q0 <= Sc - 384);

  auto keyof = [&](int c) {
    int key = (c < Gc) ? c : q0 - 272 + c;
    return min(max(key, 0), Sc - 1);
  };

  const short *kp0, *kp1, *vp0, *vp1;
  s16x8 kreg0, kreg1, vreg0, vreg1;
  auto loadRegs = [&](int ch) {
    if (!interior || ch <= 1) {
      kp0 = k + (brow + keyof(ch * 64 + krow))       * Dmc + hoff + (kcol16 >> 1);
      kp1 = k + (brow + keyof(ch * 64 + 32 + krow))  * Dmc + hoff + (kcol16 >> 1);
      vp0 = v + (brow + keyof(ch * 64 + 2 * vp))      * Dmc + hoff + vo * 8;
      vp1 = v + (brow + keyof(ch * 64 + 2 * vp + 1))  * Dmc + hoff + vo * 8;
    } else {
      kp0 += 64 * Dmc; kp1 += 64 * Dmc; vp0 += 64 * Dmc; vp1 += 64 * Dmc;
    }
    kreg0 = *(const s16x8*)kp0;
    kreg1 = *(const s16x8*)kp1;
    vreg0 = *(const s16x8*)vp0;
    vreg1 = *(const s16x8*)vp1;
  };

  loadRegs(0);

  for (int ch = 0; ch < 10; ++ch) {
    __syncthreads();
    *(s16x8*)(KsB + krow * 128        + (kcol16 ^ ((krow & 7) << 4))) = kreg0;
    *(s16x8*)(KsB + (krow + 32) * 128 + (kcol16 ^ ((krow & 7) << 4))) = kreg1;
#pragma unroll
    for (int j = 0; j < 8; ++j) {
      int d = vo * 8 + j;
      unsigned int wrd = (unsigned int)(unsigned short)vreg0[j] |
                         ((unsigned int)(unsigned short)vreg1[j] << 16);
      *(unsigned int*)(VtB + d * 128 + ((4 * vp) ^ (j << 4))) = wrd;
    }
    if (ch < 9) loadRegs(ch + 1);
    __syncthreads();

    if (ch == 9 && wid != 3) continue;

    f32x4 sac[4] = {};
    __builtin_amdgcn_s_setprio(1);
#pragma unroll
    for (int kt = 0; kt < 4; ++kt) {
      int row = kt * 16 + ql;
#pragma unroll
      for (int sl = 0; sl < 2; ++sl) {
        s16x8 af = *(const s16x8*)(KsB + row * 128 + ((lg * 16 + sl * 64) ^ ((row & 7) << 4)));
        sac[kt] = __builtin_amdgcn_mfma_f32_16x16x32_bf16(af, qf[sl], sac[kt], 0, 0, 0);
      }
    }
    __builtin_amdgcn_s_setprio(0);

    bool needMask = (ch < 2) | (ch > 7) | (q0 < 272) | (q0 > Sc - 384);
    if (needMask) {
#pragma unroll
      for (int kt = 0; kt < 4; ++kt)
#pragma unroll
        for (int r = 0; r < 4; ++r) {
          int c = ch * 64 + kt * 16 + lg * 4 + r;
          if (c >= Gc) {
            float sv = sac[kt][r];
            int jj = c - Gc - qr;
            int kp2 = q0 - 272 + c;
            bool ok = (jj >= 0) & (jj <= 2 * Wc) & (kp2 >= 0) & (kp2 < Sc);
            sac[kt][r] = ok ? (sv + ((kp2 < Gc) ? NEG2c : 0.f)) : -INFINITY;
          }
        }
    }

    float t0 = max3f(sac[0][0], sac[0][1], sac[0][2]);
    float t1 = max3f(sac[0][3], sac[1][0], sac[1][1]);
    float t2 = max3f(sac[1][2], sac[1][3], sac[2][0]);
    float t3 = max3f(sac[2][1], sac[2][2], sac[2][3]);
    float t4 = max3f(sac[3][0], sac[3][1], sac[3][2]);
    float cm = fmaxf(max3f(t0, t1, t2), max3f(t3, t4, sac[3][3]));
    cm = fmaxf(cm, __shfl_xor(cm, 16));
    cm = fmaxf(cm, __shfl_xor(cm, 32));

    if (__all(cm <= m_run + 11.5f)) {
      float cl0 = 0.f, cl1 = 0.f, cl2 = 0.f, cl3 = 0.f;
#pragma unroll
      for (int kt = 0; kt < 4; ++kt) {
        float p0 = __builtin_amdgcn_exp2f(sac[kt][0] - m_run);
        float p1 = __builtin_amdgcn_exp2f(sac[kt][1] - m_run);
        float p2 = __builtin_amdgcn_exp2f(sac[kt][2] - m_run);
        float p3 = __builtin_amdgcn_exp2f(sac[kt][3] - m_run);
        sac[kt][0] = p0; sac[kt][1] = p1; sac[kt][2] = p2; sac[kt][3] = p3;
        cl0 += p0; cl1 += p1; cl2 += p2; cl3 += p3;
      }
      float cl = (cl0 + cl1) + (cl2 + cl3);
      cl += __shfl_xor(cl, 16);
      cl += __shfl_xor(cl, 32);
      l_run += cl;
    } else {
      float m_new = fmaxf(m_run, cm);
      float scale = __builtin_amdgcn_exp2f(m_run - m_new);
      float cl0 = 0.f, cl1 = 0.f, cl2 = 0.f, cl3 = 0.f;
#pragma unroll
      for (int kt = 0; kt < 4; ++kt) {
        float p0 = __builtin_amdgcn_exp2f(sac[kt][0] - m_new);
        float p1 = __builtin_amdgcn_exp2f(sac[kt][1] - m_new);
        float p2 = __builtin_amdgcn_exp2f(sac[kt][2] - m_new);
        float p3 = __builtin_amdgcn_exp2f(sac[kt][3] - m_new);
        sac[kt][0] = p0; sac[kt][1] = p1; sac[kt][2] = p2; sac[kt][3] = p3;
        cl0 += p0; cl1 += p1; cl2 += p2; cl3 += p3;
      }
      float cl = (cl0 + cl1) + (cl2 + cl3);
      cl += __shfl_xor(cl, 16);
      cl += __shfl_xor(cl, 32);
      l_run = l_run * scale + cl;
      m_run = m_new;
#pragma unroll
      for (int rr = 0; rr < 4; ++rr) {
        float os = __shfl(scale, lg * 4 + rr);
#pragma unroll
        for (int dt = 0; dt < 4; ++dt) oacc[dt][rr] *= os;
      }
    }

    char* PsB = (char*)Ps[wid];
#pragma unroll
    for (int kt = 0; kt < 4; ++kt) {
      u32x2 pw;
      asm("v_cvt_pk_bf16_f32 %0, %1, %2" : "=v"(pw.x) : "v"(sac[kt][0]), "v"(sac[kt][1]));
      asm("v_cvt_pk_bf16_f32 %0, %1, %2" : "=v"(pw.y) : "v"(sac[kt][2]), "v"(sac[kt][3]));
      *(u32x2*)(PsB + ql * 128 + ((kt * 32 + lg * 8) ^ ((ql & 7) << 4))) = pw;
    }
    s16x8 pf[2];
#pragma unroll
    for (int ks = 0; ks < 2; ++ks)
      pf[ks] = *(const s16x8*)(PsB + ql * 128 + ((ks * 64 + lg * 16) ^ ((ql & 7) << 4)));
    __builtin_amdgcn_s_setprio(1);
#pragma unroll
    for (int dt = 0; dt < 4; ++dt) {
      int d = dt * 16 + ql;
#pragma unroll
      for (int ks = 0; ks < 2; ++ks) {
        s16x8 vf = *(const s16x8*)(VtB + d * 128 + ((ks * 64 + lg * 16) ^ ((d & 7) << 4)));
        oacc[dt] = __builtin_amdgcn_mfma_f32_16x16x32_bf16(pf[ks], vf, oacc[dt], 0, 0, 0);
      }
    }
    __builtin_amdgcn_s_setprio(0);
  }

  float inv = 1.f / l_run;
#pragma unroll
  for (int rr = 0; rr < 4; ++rr) {
    float oi = __shfl(inv, lg * 4 + rr);
    int row = q0 + wid * 16 + lg * 4 + rr;
    float* op = out + ((size_t)(b * Sc + row)) * Dmc + h * HDc + ql;
#pragma unroll
    for (int dt = 0; dt < 4; ++dt)
      op[dt * 16] = oacc[dt][rr] * oi;
  }
}

// ---------------- global rows, MFMA split-K phase A (r15-proven) ----------
__global__ __launch_bounds__(64) void global_attn_part_mfma(
    const short* __restrict__ qg, const short* __restrict__ kg,
    const short* __restrict__ vg, float* __restrict__ pml, float* __restrict__ po)
{
  const int ch = blockIdx.x, h = blockIdx.y, b = blockIdx.z;
  const int lane = threadIdx.x;

  __shared__ short Ks[4096];
  __shared__ short Vt[4096];
  __shared__ short Ps[1024];
  char* KsB = (char*)Ks;
  char* VtB = (char*)Vt;

  const int ql = lane & 15;
  const int lg = lane >> 4;

  s16x8 qf[2];
  {
    const short* qp = qg + ((size_t)(b * Gc + ql)) * Dmc + h * HDc + lg * 8;
    qf[0] = *(const s16x8*)qp;
    qf[1] = *(const s16x8*)(qp + 32);
  }

  const size_t hoff = (size_t)h * HDc;
  const size_t brow = (size_t)b * Sc;
  const int key0 = ch * 64;

  const int krow = lane >> 3, kcol16 = (lane & 7) * 16;
#pragma unroll
  for (int rr = 0; rr < 8; ++rr) {
    int row = krow + rr * 8;
    s16x8 kv = *(const s16x8*)(kg + (brow + key0 + row) * Dmc + hoff + (kcol16 >> 1));
    *(s16x8*)(KsB + row * 128 + (kcol16 ^ ((row & 7) << 4))) = kv;
  }
  const int vp = lane & 31, vo0 = lane >> 5;
#pragma unroll
  for (int oo = 0; oo < 4; ++oo) {
    int vo = vo0 + oo * 2;
    s16x8 v0 = *(const s16x8*)(vg + (brow + key0 + 2 * vp)     * Dmc + hoff + vo * 8);
    s16x8 v1 = *(const s16x8*)(vg + (brow + key0 + 2 * vp + 1) * Dmc + hoff + vo * 8);
#pragma unroll
    for (int j = 0; j < 8; ++j) {
      int d = vo * 8 + j;
      unsigned int wrd = (unsigned int)(unsigned short)v0[j] |
                         ((unsigned int)(unsigned short)v1[j] << 16);
      *(unsigned int*)(VtB + d * 128 + ((4 * vp) ^ (j << 4))) = wrd;
    }
  }

  f32x4 sac[4] = {};
#pragma unroll
  for (int kt = 0; kt < 4; ++kt) {
    int row = kt * 16 + ql;
#pragma unroll
    for (int sl = 0; sl < 2; ++sl) {
      s16x8 af = *(const s16x8*)(KsB + row * 128 + ((lg * 16 + sl * 64) ^ ((row & 7) << 4)));
      sac[kt] = __builtin_amdgcn_mfma_f32_16x16x32_bf16(af, qf[sl], sac[kt], 0, 0, 0);
    }
  }

  float t0 = max3f(sac[0][0], sac[0][1], sac[0][2]);
  float t1 = max3f(sac[0][3], sac[1][0], sac[1][1]);
  float t2 = max3f(sac[1][2], sac[1][3], sac[2][0]);
  float t3 = max3f(sac[2][1], sac[2][2], sac[2][3]);
  float t4 = max3f(sac[3][0], sac[3][1], sac[3][2]);
  float m = fmaxf(max3f(t0, t1, t2), max3f(t3, t4, sac[3][3]));
  m = fmaxf(m, __shfl_xor(m, 16));
  m = fmaxf(m, __shfl_xor(m, 32));

  float cl = 0.f;
#pragma unroll
  for (int kt = 0; kt < 4; ++kt)
#pragma unroll
    for (int r = 0; r < 4; ++r) {
      float p = __builtin_amdgcn_exp2f(sac[kt][r] - m);
      sac[kt][r] = p;
      cl += p;
    }
  cl += __shfl_xor(cl, 16);
  cl += __shfl_xor(cl, 32);

#pragma unroll
  for (int kt = 0; kt < 4; ++kt) {
    u32x2 pw;
    asm("v_cvt_pk_bf16_f32 %0, %1, %2" : "=v"(pw.x) : "v"(sac[kt][0]), "v"(sac[kt][1]));
    asm("v_cvt_pk_bf16_f32 %0, %1, %2" : "=v"(pw.y) : "v"(sac[kt][2]), "v"(sac[kt][3]));
    *(u32x2*)((char*)Ps + ql * 128 + ((kt * 32 + lg * 8) ^ ((ql & 7) << 4))) = pw;
  }
  s16x8 pf[2];
#pragma unroll
  for (int ks = 0; ks < 2; ++ks)
    pf[ks] = *(const s16x8*)((char*)Ps + ql * 128 + ((ks * 64 + lg * 16) ^ ((ql & 7) << 4)));

  f32x4 oacc[4] = {};
#pragma unroll
  for (int dt = 0; dt < 4; ++dt) {
    int d = dt * 16 + ql;
#pragma unroll
    for (int ks = 0; ks < 2; ++ks) {
      s16x8 vf = *(const s16x8*)(VtB + d * 128 + ((ks * 64 + lg * 16) ^ ((d & 7) << 4)));
      oacc[dt] = __builtin_amdgcn_mfma_f32_16x16x32_bf16(pf[ks], vf, oacc[dt], 0, 0, 0);
    }
  }

  const size_t slot = ((size_t)(b * Hc + h) * NCHG + ch);
  float* pob = po + slot * 1024;
#pragma unroll
  for (int rr = 0; rr < 4; ++rr) {
    int qrow = lg * 4 + rr;
#pragma unroll
    for (int dt = 0; dt < 4; ++dt)
      pob[qrow * 64 + dt * 16 + ql] = oacc[dt][rr];
  }
  if (lg == 0) {
    pml[(slot * 16 + ql) * 2]     = m;
    pml[(slot * 16 + ql) * 2 + 1] = cl;
  }
}

// ---------------- global rows, split-K phase B: combine 64 partials ----------
__global__ __launch_bounds__(64) void global_attn_comb(
    const float* __restrict__ pml, const float* __restrict__ po,
    float* __restrict__ out)
{
  const int i = blockIdx.x, h = blockIdx.y, b = blockIdx.z;
  const int d = threadIdx.x;
  const size_t base = (size_t)(b * Hc + h) * NCHG;

  float m = -INFINITY;
#pragma unroll 8
  for (int ch = 0; ch < NCHG; ++ch) m = fmaxf(m, pml[((base + ch) * 16 + i) * 2]);
  float l = 0.f, o = 0.f;
#pragma unroll 8
  for (int ch = 0; ch < NCHG; ++ch) {
    float wgt = __builtin_amdgcn_exp2f(pml[((base + ch) * 16 + i) * 2] - m);
    l = fmaf(pml[((base + ch) * 16 + i) * 2 + 1], wgt, l);
    o = fmaf(po[(base + ch) * 1024 + i * 64 + d], wgt, o);
  }
  out[((size_t)(b * Sc + i)) * Dmc + h * HDc + d] = o / l;
}

extern "C" void kernel_launch(void* const* d_in, const int* in_sizes, int n_in,
                              void* d_out, int out_size, void* d_ws, size_t ws_size,
                              hipStream_t stream) {
  const float* hs  = (const float*)d_in[0];
  const float* Wq  = (const float*)d_in[1];
  const float* bq  = (const float*)d_in[2];
  const float* Wk  = (const float*)d_in[3];
  const float* bk  = (const float*)d_in[4];
  const float* Wv  = (const float*)d_in[5];
  const float* bv  = (const float*)d_in[6];
  const float* Wqg = (const float*)d_in[7];
  const float* bqg = (const float*)d_in[8];
  const float* Wkg = (const float*)d_in[9];
  const float* bkg = (const float*)d_in[10];
  const float* Wvg = (const float*)d_in[11];
  const float* bvg = (const float*)d_in[12];
  float* out = (float*)d_out;

  char* ws = (char*)d_ws;
  const size_t bufB = (size_t)Bc * Sc * Dmc * sizeof(short);   // 12,582,912
  const size_t wt5B = 5ull * Dmc * Dmc * sizeof(short);        // 5,898,240
  short* hsb = (short*)(ws);
  short* qb  = (short*)(ws + bufB);       // q, k at +BUFE, v at +2*BUFE

  dim3 bb(256);

  if (ws_size >= 4 * bufB + wt5B) {
    // ---------- merged path ----------
    short* wt5 = (short*)(ws + 4 * bufB);
    short* qgb = (short*)(ws);                    // hsb dead after gemm_all
    float* pml = (float*)(ws + 262144);
    float* po  = (float*)(ws + (1u << 20));
    short* kgb = (short*)d_out;                   // kg | vg fill d_out exactly
    short* vgb = kgb + BUFE;

    prep_fused<<<dim3(5952), bb, 0, stream>>>(hs, hsb, Wq, Wk, Wv, Wkg, Wvg, wt5);
    gemm_all<<<dim3(64, 30), bb, 0, stream>>>(hsb, wt5, bq, bk, bv, bkg, bvg,
                                              qb, kgb, SCALE2q);
    qg_proj<<<dim3(32, 12), bb, 0, stream>>>(hs, Wqg, bqg, qgb);
    global_attn_part_mfma<<<dim3(NCHG, Hc, Bc), dim3(64), 0, stream>>>(qgb, kgb, vgb, pml, po);
    local_attn_mfma<<<dim3(64, Hc, Bc), bb, 0, stream>>>(qb, qb + BUFE, qb + 2 * BUFE, out);
    global_attn_comb<<<dim3(Gc, Hc, Bc), dim3(64), 0, stream>>>(pml, po, out);
  } else {
    // ---------- fallback: r15 sequence ----------
    short* wtA = (short*)d_out;
    short* qgb = (short*)(ws + 3 * bufB);
    float* pml = (float*)(ws + 3 * bufB + 262144);
    float* po  = (float*)(ws + 3 * bufB + (1u << 20));
    short* wtD = (short*)(ws + 3 * bufB + (8u << 20));
    short* kgb = qb;
    short* vgb = qb + BUFE;

    conv_bf16<<<dim3(3072), bb, 0, stream>>>(hs, hsb);
    transpose_w5<<<dim3(24, 24, 3), bb, 0, stream>>>(Wq, Wk, Wv, Wv, Wv, wtA);
    gemm_all<<<dim3(64, 18), bb, 0, stream>>>(hsb, wtA, bq, bk, bv, bv, bv,
                                              qb, qb, SCALE2q);
    local_attn_mfma<<<dim3(64, Hc, Bc), bb, 0, stream>>>(qb, qb + BUFE, qb + 2 * BUFE, out);
    transpose_w5<<<dim3(24, 24, 2), bb, 0, stream>>>(Wkg, Wvg, Wvg, Wvg, Wvg, wtD);
    gemm_all<<<dim3(64, 12), bb, 0, stream>>>(hsb, wtD, bkg, bvg, bvg, bvg, bvg,
                                              kgb, kgb, 1.0f);
    qg_proj<<<dim3(32, 12), bb, 0, stream>>>(hs, Wqg, bqg, qgb);
    global_attn_part_mfma<<<dim3(NCHG, Hc, Bc), dim3(64), 0, stream>>>(qgb, kgb, vgb, pml, po);
    global_attn_comb<<<dim3(Gc, Hc, Bc), dim3(64), 0, stream>>>(pml, po, out);
  }
}